// Round 1
// baseline (310.791 us; speedup 1.0000x reference)
//
#include <hip/hip_runtime.h>

#define DI __device__ __forceinline__

typedef unsigned short u16;
typedef short short8 __attribute__((ext_vector_type(8)));
typedef float f32x4 __attribute__((ext_vector_type(4)));
typedef u16 u16x4 __attribute__((ext_vector_type(4)));

// round-to-nearest-even f32 -> bf16
DI u16 f2bf(float f){
    unsigned u = __builtin_bit_cast(unsigned, f);
    u += 0x7FFFu + ((u >> 16) & 1u);
    return (u16)(u >> 16);
}

#if defined(__has_builtin)
#if __has_builtin(__builtin_amdgcn_global_load_lds)
#define HAS_GLL 1
#endif
#endif

DI void async16(u16* lds, const u16* g){
#ifdef HAS_GLL
    __builtin_amdgcn_global_load_lds(
        (const __attribute__((address_space(1))) unsigned int*)g,
        (__attribute__((address_space(3))) unsigned int*)lds, 16, 0, 0);
#else
    *(short8*)lds = *(const short8*)g;
#endif
}

// ---------------- constants ----------------
// B=2, N=2048, DIM_IN=DIM_K=DIM_V=1024, NH=16, hd=64
#define SEQ   2048
#define DIN   1024
#define MTOT  4096   // B*N

// ---------------- convert x to bf16 ----------------
__global__ void k_cvt_x(const float* __restrict__ x, u16* __restrict__ xb){
    int i = (blockIdx.x * 256 + threadIdx.x) * 4;
    f32x4 v = *(const f32x4*)(x + i);
    u16x4 o;
    for (int j = 0; j < 4; j++) o[j] = f2bf(v[j]);
    *(u16x4*)(xb + i) = o;
}

// ---------------- transpose W [K][N] -> Wt [N][K] bf16 ----------------
__global__ void k_tw(const float* __restrict__ W, u16* __restrict__ Wt){
    __shared__ float t[32][33];
    int tx = threadIdx.x, ty = threadIdx.y;           // (32,8)
    int n0 = blockIdx.x * 32, k0 = blockIdx.y * 32;
    for (int i = 0; i < 4; i++)
        t[ty + i*8][tx] = W[(size_t)(k0 + ty + i*8) * DIN + n0 + tx];
    __syncthreads();
    for (int i = 0; i < 4; i++)
        Wt[(size_t)(n0 + ty + i*8) * DIN + k0 + tx] = f2bf(t[tx][ty + i*8]);
}

// ---------------- projection GEMM ----------------
// C[m][c] = sum_k A[m][k] * Wt[c][k] + bias[c]    (A: xb [4096][1024], Wt: [1024][1024])
// MODE 0: Q -> (val+b)*0.125, layout [bh][n][64]
// MODE 1: K -> val+b,         layout [bh][n][64]
// MODE 2: V -> val+b,         layout [bh][dv][n]  (transposed)
template<int MODE>
__global__ __launch_bounds__(256) void k_proj(const u16* __restrict__ A,
                                              const u16* __restrict__ Bt,
                                              const float* __restrict__ bias,
                                              u16* __restrict__ out){
    __shared__ u16 As[128 * 32];
    __shared__ u16 Bs[128 * 32];
    int tid = threadIdx.x;
    int l = tid & 63, w = tid >> 6;
    int lq = l & 15, lg = l >> 4;
    int wm = w >> 1, wn = w & 1;
    int m0 = blockIdx.x * 128, n0 = blockIdx.y * 128;

    f32x4 acc[4][4] = {};

    for (int k0 = 0; k0 < DIN; k0 += 32){
        for (int i = 0; i < 2; i++){
            int eo  = i * 2048 + tid * 8;
            int row = eo >> 5, col = eo & 31;
            async16(&As[eo], A  + (size_t)(m0 + row) * DIN + k0 + col);
            async16(&Bs[eo], Bt + (size_t)(n0 + row) * DIN + k0 + col);
        }
        __syncthreads();
        short8 af[4], bf[4];
        for (int f = 0; f < 4; f++){
            af[f] = *(const short8*)&As[(wm*64 + f*16 + lq) * 32 + lg * 8];
            bf[f] = *(const short8*)&Bs[(wn*64 + f*16 + lq) * 32 + lg * 8];
        }
        for (int fm = 0; fm < 4; fm++)
            for (int fn = 0; fn < 4; fn++)
                acc[fm][fn] = __builtin_amdgcn_mfma_f32_16x16x32_bf16(af[fm], bf[fn], acc[fm][fn], 0, 0, 0);
        __syncthreads();
    }

    for (int fn = 0; fn < 4; fn++){
        int cc = n0 + wn*64 + fn*16 + lq;           // global output column 0..1023
        float bv = bias[cc];
        int h = cc >> 6, d = cc & 63;
        for (int fm = 0; fm < 4; fm++){
            int mbase = m0 + wm*64 + fm*16 + lg*4;  // global row (b*2048+n)
            int b = mbase >> 11, n = mbase & 2047;
            if (MODE == 2){
                u16x4 pv;
                for (int r = 0; r < 4; r++) pv[r] = f2bf(acc[fm][fn][r] + bv);
                *(u16x4*)&out[((size_t)(b*16 + h) * 64 + d) * SEQ + n] = pv;
            } else {
                for (int r = 0; r < 4; r++){
                    float v = acc[fm][fn][r] + bv;
                    if (MODE == 0) v *= 0.125f;
                    out[((size_t)(b*16 + h) * SEQ + (n + r)) * 64 + d] = f2bf(v);
                }
            }
        }
    }
}

// ---------------- flash attention ----------------
// Q,K: [bh][n][64] bf16 (Q pre-scaled by 1/8), Vt: [bh][dv][n] bf16
// out: [b][n][1024] fp32
__global__ __launch_bounds__(256) void k_attn(const u16* __restrict__ Q,
                                              const u16* __restrict__ K,
                                              const u16* __restrict__ Vt,
                                              float* __restrict__ out){
    __shared__ u16 P[4][16][64];                    // per-wave P tile, XOR-swizzled rows
    int tid = threadIdx.x, l = tid & 63, w = tid >> 6;
    int lq = l & 15, lg = l >> 4;
    int bh = blockIdx.y;                            // 0..31
    int b = bh >> 4, h = bh & 15;
    int q0 = blockIdx.x * 64 + w * 16;

    const u16* Qb = Q  + (size_t)bh * SEQ * 64;
    const u16* Kb = K  + (size_t)bh * SEQ * 64;
    const u16* Vb = Vt + (size_t)bh * 64 * SEQ;

    short8 qf[2];
    for (int dh = 0; dh < 2; dh++)
        qf[dh] = *(const short8*)(Qb + (size_t)(q0 + lq) * 64 + dh*32 + lg*8);

    float ms = -INFINITY, ls = 0.f;
    f32x4 o[4] = {};
    char* prow = (char*)&P[w][lq][0];               // 128B row for this lane's q
    int swz = (lq & 7) << 4;                        // XOR swizzle of byte offset

    for (int kv0 = 0; kv0 < SEQ; kv0 += 64){
        // S^T tile: St[kc][q] for kc in [kv0, kv0+64), this lane holds q=lq
        f32x4 st[4];
        for (int sub = 0; sub < 4; sub++){
            st[sub] = (f32x4){0.f, 0.f, 0.f, 0.f};
            for (int dh = 0; dh < 2; dh++){
                short8 kf = *(const short8*)(Kb + (size_t)(kv0 + sub*16 + lq) * 64 + dh*32 + lg*8);
                st[sub] = __builtin_amdgcn_mfma_f32_16x16x32_bf16(kf, qf[dh], st[sub], 0, 0, 0);
            }
        }
        // online softmax for row q=lq (values spread over 4 lanes: l, l^16, l^32, l^48)
        float pm = st[0][0];
        for (int sub = 0; sub < 4; sub++)
            for (int r = 0; r < 4; r++) pm = fmaxf(pm, st[sub][r]);
        pm = fmaxf(pm, __shfl_xor(pm, 16));
        pm = fmaxf(pm, __shfl_xor(pm, 32));
        float mn  = fmaxf(ms, pm);
        float fac = __expf(ms - mn);
        float psum = 0.f;
        for (int sub = 0; sub < 4; sub++){
            f32x4 p;
            for (int r = 0; r < 4; r++){ p[r] = __expf(st[sub][r] - mn); psum += p[r]; }
            u16x4 pk;
            for (int r = 0; r < 4; r++) pk[r] = f2bf(p[r]);
            *(u16x4*)(prow + (((sub*32 + lg*8)) ^ swz)) = pk;   // P[q=lq][kc=sub*16+lg*4 ..]
        }
        psum += __shfl_xor(psum, 16);
        psum += __shfl_xor(psum, 32);
        ls = ls * fac + psum;
        ms = mn;
        asm volatile("s_waitcnt lgkmcnt(0)" ::: "memory");
        __builtin_amdgcn_sched_barrier(0);
        // rescale O (O-fragment rows are q = lg*4+r; fetch factors from lane q)
        f32x4 fv;
        for (int r = 0; r < 4; r++) fv[r] = __shfl(fac, lg*4 + r);
        for (int fn = 0; fn < 4; fn++) o[fn] *= fv;
        // PV: O[q][dv] += P[q][kc] * V[kc][dv]
        for (int kc2 = 0; kc2 < 2; kc2++){
            char* pr2 = (char*)&P[w][lq][0];
            short8 pf = *(const short8*)(pr2 + (((kc2*64 + lg*16)) ^ swz));
            for (int fn = 0; fn < 4; fn++){
                short8 vf = *(const short8*)(Vb + (size_t)(fn*16 + lq) * SEQ + kv0 + kc2*32 + lg*8);
                o[fn] = __builtin_amdgcn_mfma_f32_16x16x32_bf16(pf, vf, o[fn], 0, 0, 0);
            }
        }
        asm volatile("s_waitcnt lgkmcnt(0)" ::: "memory");
        __builtin_amdgcn_sched_barrier(0);
    }

    f32x4 lv;
    for (int r = 0; r < 4; r++) lv[r] = 1.0f / __shfl(ls, lg*4 + r);
    for (int fn = 0; fn < 4; fn++){
        int dv = h*64 + fn*16 + lq;
        for (int r = 0; r < 4; r++){
            int n = q0 + lg*4 + r;
            out[((size_t)b * SEQ + n) * 1024 + dv] = o[fn][r] * lv[r];
        }
    }
}

// ---------------- launcher ----------------
extern "C" void kernel_launch(void* const* d_in, const int* in_sizes, int n_in,
                              void* d_out, int out_size, void* d_ws, size_t ws_size,
                              hipStream_t stream){
    const float* x  = (const float*)d_in[0];
    const float* Wq = (const float*)d_in[1];
    const float* bq = (const float*)d_in[2];
    const float* Wk = (const float*)d_in[3];
    const float* bk = (const float*)d_in[4];
    const float* Wv = (const float*)d_in[5];
    const float* bv = (const float*)d_in[6];
    float* out = (float*)d_out;

    if (ws_size < ((size_t)38 << 20)) return;  // need 38 MB scratch

    char* ws = (char*)d_ws;
    u16* xb  = (u16*)(ws);                       // 8 MB: x bf16 [4096][1024]
    u16* wtq = (u16*)(ws + ((size_t) 8 << 20));  // 2 MB each: Wt bf16 [1024][1024]
    u16* wtk = (u16*)(ws + ((size_t)10 << 20));
    u16* wtv = (u16*)(ws + ((size_t)12 << 20));
    u16* qb  = (u16*)(ws + ((size_t)14 << 20));  // 8 MB: Q  [32][2048][64]
    u16* kb  = (u16*)(ws + ((size_t)22 << 20));  // 8 MB: K  [32][2048][64]
    u16* vtb = (u16*)(ws + ((size_t)30 << 20));  // 8 MB: Vt [32][64][2048]

    k_cvt_x<<<4096, 256, 0, stream>>>(x, xb);
    dim3 tb(32, 8);
    k_tw<<<dim3(32, 32), tb, 0, stream>>>(Wq, wtq);
    k_tw<<<dim3(32, 32), tb, 0, stream>>>(Wk, wtk);
    k_tw<<<dim3(32, 32), tb, 0, stream>>>(Wv, wtv);

    dim3 gg(32, 8);                              // 4096/128 x 1024/128
    k_proj<0><<<gg, 256, 0, stream>>>(xb, wtq, bq, qb);
    k_proj<1><<<gg, 256, 0, stream>>>(xb, wtk, bk, kb);
    k_proj<2><<<gg, 256, 0, stream>>>(xb, wtv, bv, vtb);

    k_attn<<<dim3(32, 32), 256, 0, stream>>>(qb, kb, vtb, out);
}

// Round 2
// 209.086 us; speedup vs baseline: 1.4864x; 1.4864x over previous
//
#include <hip/hip_runtime.h>

#define DI __device__ __forceinline__

typedef unsigned short u16;
typedef short short8 __attribute__((ext_vector_type(8)));
typedef float f32x4 __attribute__((ext_vector_type(4)));
typedef float f32x16 __attribute__((ext_vector_type(16)));
typedef u16 u16x4 __attribute__((ext_vector_type(4)));
typedef unsigned u32x4 __attribute__((ext_vector_type(4)));
typedef int i32x2 __attribute__((ext_vector_type(2)));

// round-to-nearest-even f32 -> bf16
DI u16 f2bf(float f){
    unsigned u = __builtin_bit_cast(unsigned, f);
    u += 0x7FFFu + ((u >> 16) & 1u);
    return (u16)(u >> 16);
}

#if defined(__has_builtin)
#if __has_builtin(__builtin_amdgcn_global_load_lds)
#define HAS_GLL 1
#endif
#if __has_builtin(__builtin_amdgcn_exp2f)
#define HAS_EXP2 1
#endif
#if __has_builtin(__builtin_amdgcn_permlane32_swap)
#define HAS_PL32 1
#endif
#endif

DI void async16(u16* lds, const u16* g){
#ifdef HAS_GLL
    __builtin_amdgcn_global_load_lds(
        (const __attribute__((address_space(1))) unsigned int*)g,
        (__attribute__((address_space(3))) unsigned int*)lds, 16, 0, 0);
#else
    *(short8*)lds = *(const short8*)g;
#endif
}

DI float ex2(float x){
#ifdef HAS_EXP2
    return __builtin_amdgcn_exp2f(x);
#else
    return exp2f(x);
#endif
}

// v_cvt_pk_bf16_f32: word = (bf16(lo) | bf16(hi)<<16)
DI unsigned cvtpk(float lo, float hi){
    unsigned r;
    asm("v_cvt_pk_bf16_f32 %0, %1, %2" : "=v"(r) : "v"(lo), "v"(hi));
    return r;
}

// permlane32_swap: ret[0] = {a[0:31], b[0:31]}, ret[1] = {a[32:63], b[32:63]}
DI i32x2 plswap(int a, int b){
#ifdef HAS_PL32
    return __builtin_amdgcn_permlane32_swap(a, b, false, false);
#else
    i32x2 r;
    int ax = __shfl_xor(a, 32), bx = __shfl_xor(b, 32);
    int hi = (threadIdx.x & 63) >> 5;
    r[0] = hi ? bx : a;
    r[1] = hi ? b : ax;
    return r;
#endif
}

// ---------------- constants ----------------
// B=2, N=2048, DIM_IN=DIM_K=DIM_V=1024, NH=16, hd=64
#define SEQ   2048
#define DIN   1024
#define MTOT  4096   // B*N
// Q prescale: (1/sqrt(64)) * log2(e) so softmax runs in exp2 domain
#define QSCALE 0.18033688011112042f
#define THR2   11.5f   // defer-max threshold (8 in ln domain)

// ---------------- convert x to bf16 ----------------
__global__ void k_cvt_x(const float* __restrict__ x, u16* __restrict__ xb){
    int i = (blockIdx.x * 256 + threadIdx.x) * 4;
    f32x4 v = *(const f32x4*)(x + i);
    u16x4 o;
    for (int j = 0; j < 4; j++) o[j] = f2bf(v[j]);
    *(u16x4*)(xb + i) = o;
}

// ---------------- transpose W [K][N] -> Wt [N][K] bf16 ----------------
__global__ void k_tw(const float* __restrict__ W, u16* __restrict__ Wt){
    __shared__ float t[32][33];
    int tx = threadIdx.x, ty = threadIdx.y;           // (32,8)
    int n0 = blockIdx.x * 32, k0 = blockIdx.y * 32;
    for (int i = 0; i < 4; i++)
        t[ty + i*8][tx] = W[(size_t)(k0 + ty + i*8) * DIN + n0 + tx];
    __syncthreads();
    for (int i = 0; i < 4; i++)
        Wt[(size_t)(n0 + ty + i*8) * DIN + k0 + tx] = f2bf(t[tx][ty + i*8]);
}

// ---------------- projection GEMM ----------------
// C[m][c] = sum_k A[m][k] * Wt[c][k] + bias[c]
// MODE 0: Q -> (val+b)*QSCALE, layout [bh][n][64]
// MODE 1: K -> val+b,          layout [bh][n][64]
// MODE 2: V -> val+b,          layout [bh][dv][n]  (transposed)
template<int MODE>
__global__ __launch_bounds__(256) void k_proj(const u16* __restrict__ A,
                                              const u16* __restrict__ Bt,
                                              const float* __restrict__ bias,
                                              u16* __restrict__ out){
    __shared__ u16 As[128 * 32];
    __shared__ u16 Bs[128 * 32];
    int tid = threadIdx.x;
    int l = tid & 63, w = tid >> 6;
    int lq = l & 15, lg = l >> 4;
    int wm = w >> 1, wn = w & 1;
    int m0 = blockIdx.x * 128, n0 = blockIdx.y * 128;

    f32x4 acc[4][4] = {};

    for (int k0 = 0; k0 < DIN; k0 += 32){
        for (int i = 0; i < 2; i++){
            int eo  = i * 2048 + tid * 8;
            int row = eo >> 5, col = eo & 31;
            async16(&As[eo], A  + (size_t)(m0 + row) * DIN + k0 + col);
            async16(&Bs[eo], Bt + (size_t)(n0 + row) * DIN + k0 + col);
        }
        __syncthreads();
        short8 af[4], bf[4];
        for (int f = 0; f < 4; f++){
            af[f] = *(const short8*)&As[(wm*64 + f*16 + lq) * 32 + lg * 8];
            bf[f] = *(const short8*)&Bs[(wn*64 + f*16 + lq) * 32 + lg * 8];
        }
        for (int fm = 0; fm < 4; fm++)
            for (int fn = 0; fn < 4; fn++)
                acc[fm][fn] = __builtin_amdgcn_mfma_f32_16x16x32_bf16(af[fm], bf[fn], acc[fm][fn], 0, 0, 0);
        __syncthreads();
    }

    for (int fn = 0; fn < 4; fn++){
        int cc = n0 + wn*64 + fn*16 + lq;           // global output column 0..1023
        float bv = bias[cc];
        int h = cc >> 6, d = cc & 63;
        for (int fm = 0; fm < 4; fm++){
            int mbase = m0 + wm*64 + fm*16 + lg*4;  // global row (b*2048+n)
            int b = mbase >> 11, n = mbase & 2047;
            if (MODE == 2){
                u16x4 pv;
                for (int r = 0; r < 4; r++) pv[r] = f2bf(acc[fm][fn][r] + bv);
                *(u16x4*)&out[((size_t)(b*16 + h) * 64 + d) * SEQ + n] = pv;
            } else {
                for (int r = 0; r < 4; r++){
                    float v = acc[fm][fn][r] + bv;
                    if (MODE == 0) v *= QSCALE;
                    out[((size_t)(b*16 + h) * SEQ + (n + r)) * 64 + d] = f2bf(v);
                }
            }
        }
    }
}

// ---------------- flash attention (32x32 MFMA, in-register softmax) ----------------
// Q,K: [bh][n][64] bf16 (Q pre-scaled by QSCALE), Vt: [bh][dv][n] bf16
// out: [b][n][1024] fp32
// 4 waves/block, each wave owns 32 q-rows. No LDS, no barriers.
// Swapped QK^T: St[kc][q] = K · Q^T, so lane (l&31) holds q-row (l&31)'s scores;
// lanes l and l^32 hold complementary kc halves.
#define MFMA32(a, b, c) __builtin_amdgcn_mfma_f32_32x32x16_bf16(a, b, c, 0, 0, 0)

// build PV A-fragment (16 kc) from 8 exp'd f32 score regs via cvt_pk + permlane32_swap
#define MAKE_PA(dst, S, base) {                                   \
    unsigned a0 = cvtpk(S[base+0], S[base+1]);                    \
    unsigned a1 = cvtpk(S[base+2], S[base+3]);                    \
    unsigned b0 = cvtpk(S[base+4], S[base+5]);                    \
    unsigned b1 = cvtpk(S[base+6], S[base+7]);                    \
    i32x2 r0 = plswap((int)a0, (int)b0);                          \
    i32x2 r1 = plswap((int)a1, (int)b1);                          \
    u32x4 wv = {(unsigned)r0[0], (unsigned)r1[0],                 \
                (unsigned)r0[1], (unsigned)r1[1]};                \
    dst = __builtin_bit_cast(short8, wv); }

__global__ __launch_bounds__(256) void k_attn(const u16* __restrict__ Q,
                                              const u16* __restrict__ K,
                                              const u16* __restrict__ Vt,
                                              float* __restrict__ out){
    int tid = threadIdx.x, l = tid & 63, w = tid >> 6;
    int lq = l & 31, hi = l >> 5;
    int bh = blockIdx.y;                            // 0..31
    int b = bh >> 4, h = bh & 15;
    int q0 = blockIdx.x * 128 + w * 32;

    const u16* Qb = Q  + (size_t)bh * SEQ * 64;
    const u16* Kb = K  + (size_t)bh * SEQ * 64;
    const u16* Vb = Vt + (size_t)bh * 64 * SEQ;

    // Q fragments: B-operand, col=q=lq, k = ks*16 + hi*8 + 0..7
    short8 qf[4];
    #pragma unroll
    for (int ks = 0; ks < 4; ks++)
        qf[ks] = *(const short8*)(Qb + (size_t)(q0 + lq) * 64 + ks*16 + hi*8);

    float m = -INFINITY, ls = 0.f;
    f32x16 o0 = {}, o1 = {};

    for (int kv0 = 0; kv0 < SEQ; kv0 += 64){
        // ---- QK^T: St[kc][q], kc tiles [0,32) and [32,64) ----
        f32x16 st0 = {}, st1 = {};
        #pragma unroll
        for (int ks = 0; ks < 4; ks++){
            short8 ka = *(const short8*)(Kb + (size_t)(kv0 + lq)      * 64 + ks*16 + hi*8);
            short8 kb = *(const short8*)(Kb + (size_t)(kv0 + 32 + lq) * 64 + ks*16 + hi*8);
            st0 = MFMA32(ka, qf[ks], st0);
            st1 = MFMA32(kb, qf[ks], st1);
        }

        // ---- row max (own half), 4 parallel chains then combine ----
        float p0 = fmaxf(st0[0], st1[0]), p1 = fmaxf(st0[1], st1[1]);
        float p2 = fmaxf(st0[2], st1[2]), p3 = fmaxf(st0[3], st1[3]);
        #pragma unroll
        for (int r = 4; r < 16; r += 4){
            p0 = fmaxf(p0, fmaxf(st0[r+0], st1[r+0]));
            p1 = fmaxf(p1, fmaxf(st0[r+1], st1[r+1]));
            p2 = fmaxf(p2, fmaxf(st0[r+2], st1[r+2]));
            p3 = fmaxf(p3, fmaxf(st0[r+3], st1[r+3]));
        }
        float pm = fmaxf(fmaxf(p0, p1), fmaxf(p2, p3));
        pm = fmaxf(pm, __shfl_xor(pm, 32));         // combine kc halves

        // ---- defer-max rescale (rare) ----
        if (__any(pm > m + THR2)){
            float mn  = fmaxf(m, pm);
            float fac = ex2(m - mn);                // m=-inf -> 0
            m = mn;
            ls *= fac;
            #pragma unroll
            for (int r = 0; r < 16; r++){
                int row = (r & 3) + 8*(r >> 2) + 4*hi;
                float f = __shfl(fac, row);
                o0[r] *= f; o1[r] *= f;
            }
        }

        // ---- P = exp2(S - m), sum ----
        float psum = 0.f;
        #pragma unroll
        for (int r = 0; r < 16; r++){
            st0[r] = ex2(st0[r] - m); psum += st0[r];
            st1[r] = ex2(st1[r] - m); psum += st1[r];
        }
        psum += __shfl_xor(psum, 32);
        ls += psum;

        // ---- P -> bf16 A-fragments, in-register ----
        short8 pa0, pa1, pa2, pa3;
        MAKE_PA(pa0, st0, 0)
        MAKE_PA(pa1, st0, 8)
        MAKE_PA(pa2, st1, 0)
        MAKE_PA(pa3, st1, 8)

        // ---- PV: O[q][dv] += P[q][kc] * V[kc][dv] ----
        #pragma unroll
        for (int kct = 0; kct < 4; kct++){
            short8 pf = (kct == 0) ? pa0 : (kct == 1) ? pa1 : (kct == 2) ? pa2 : pa3;
            short8 v0 = *(const short8*)(Vb + (size_t)lq        * SEQ + kv0 + kct*16 + hi*8);
            short8 v1 = *(const short8*)(Vb + (size_t)(32 + lq) * SEQ + kv0 + kct*16 + hi*8);
            o0 = MFMA32(pf, v0, o0);
            o1 = MFMA32(pf, v1, o1);
        }
    }

    // ---- epilogue: divide by ls per row, write fp32 ----
    #pragma unroll
    for (int r = 0; r < 16; r++){
        int row = (r & 3) + 8*(r >> 2) + 4*hi;
        float inv = 1.0f / __shfl(ls, row);
        float* op = out + ((size_t)b * SEQ + (q0 + row)) * 1024 + h*64 + lq;
        op[0]  = o0[r] * inv;
        op[32] = o1[r] * inv;
    }
}

// ---------------- launcher ----------------
extern "C" void kernel_launch(void* const* d_in, const int* in_sizes, int n_in,
                              void* d_out, int out_size, void* d_ws, size_t ws_size,
                              hipStream_t stream){
    const float* x  = (const float*)d_in[0];
    const float* Wq = (const float*)d_in[1];
    const float* bq = (const float*)d_in[2];
    const float* Wk = (const float*)d_in[3];
    const float* bk = (const float*)d_in[4];
    const float* Wv = (const float*)d_in[5];
    const float* bv = (const float*)d_in[6];
    float* out = (float*)d_out;

    if (ws_size < ((size_t)38 << 20)) return;  // need 38 MB scratch

    char* ws = (char*)d_ws;
    u16* xb  = (u16*)(ws);                       // 8 MB: x bf16 [4096][1024]
    u16* wtq = (u16*)(ws + ((size_t) 8 << 20));  // 2 MB each: Wt bf16 [1024][1024]
    u16* wtk = (u16*)(ws + ((size_t)10 << 20));
    u16* wtv = (u16*)(ws + ((size_t)12 << 20));
    u16* qb  = (u16*)(ws + ((size_t)14 << 20));  // 8 MB: Q  [32][2048][64]
    u16* kb  = (u16*)(ws + ((size_t)22 << 20));  // 8 MB: K  [32][2048][64]
    u16* vtb = (u16*)(ws + ((size_t)30 << 20));  // 8 MB: Vt [32][64][2048]

    k_cvt_x<<<4096, 256, 0, stream>>>(x, xb);
    dim3 tb(32, 8);
    k_tw<<<dim3(32, 32), tb, 0, stream>>>(Wq, wtq);
    k_tw<<<dim3(32, 32), tb, 0, stream>>>(Wk, wtk);
    k_tw<<<dim3(32, 32), tb, 0, stream>>>(Wv, wtv);

    dim3 gg(32, 8);                              // 4096/128 x 1024/128
    k_proj<0><<<gg, 256, 0, stream>>>(xb, wtq, bq, qb);
    k_proj<1><<<gg, 256, 0, stream>>>(xb, wtk, bk, kb);
    k_proj<2><<<gg, 256, 0, stream>>>(xb, wtv, bv, vtb);

    k_attn<<<dim3(16, 32), 256, 0, stream>>>(qb, kb, vtb, out);
}

// Round 3
// 205.532 us; speedup vs baseline: 1.5121x; 1.0173x over previous
//
#include <hip/hip_runtime.h>

#define DI __device__ __forceinline__

typedef unsigned short u16;
typedef short short8 __attribute__((ext_vector_type(8)));
typedef float f32x4 __attribute__((ext_vector_type(4)));
typedef float f32x16 __attribute__((ext_vector_type(16)));
typedef u16 u16x4 __attribute__((ext_vector_type(4)));
typedef unsigned u32x4 __attribute__((ext_vector_type(4)));
typedef int i32x2 __attribute__((ext_vector_type(2)));

// round-to-nearest-even f32 -> bf16
DI u16 f2bf(float f){
    unsigned u = __builtin_bit_cast(unsigned, f);
    u += 0x7FFFu + ((u >> 16) & 1u);
    return (u16)(u >> 16);
}

#if defined(__has_builtin)
#if __has_builtin(__builtin_amdgcn_global_load_lds)
#define HAS_GLL 1
#endif
#if __has_builtin(__builtin_amdgcn_exp2f)
#define HAS_EXP2 1
#endif
#if __has_builtin(__builtin_amdgcn_permlane32_swap)
#define HAS_PL32 1
#endif
#endif

DI void async16(u16* lds, const u16* g){
#ifdef HAS_GLL
    __builtin_amdgcn_global_load_lds(
        (const __attribute__((address_space(1))) unsigned int*)g,
        (__attribute__((address_space(3))) unsigned int*)lds, 16, 0, 0);
#else
    *(short8*)lds = *(const short8*)g;
#endif
}

DI float ex2(float x){
#ifdef HAS_EXP2
    return __builtin_amdgcn_exp2f(x);
#else
    return exp2f(x);
#endif
}

// v_cvt_pk_bf16_f32: word = (bf16(lo) | bf16(hi)<<16)
DI unsigned cvtpk(float lo, float hi){
    unsigned r;
    asm("v_cvt_pk_bf16_f32 %0, %1, %2" : "=v"(r) : "v"(lo), "v"(hi));
    return r;
}

// permlane32_swap: ret[0] = {a[0:31], b[0:31]}, ret[1] = {a[32:63], b[32:63]}
DI i32x2 plswap(int a, int b){
#ifdef HAS_PL32
    return __builtin_amdgcn_permlane32_swap(a, b, false, false);
#else
    i32x2 r;
    int ax = __shfl_xor(a, 32), bx = __shfl_xor(b, 32);
    int hi = (threadIdx.x & 63) >> 5;
    r[0] = hi ? bx : a;
    r[1] = hi ? b : ax;
    return r;
#endif
}

// ---------------- constants ----------------
// B=2, N=2048, DIM_IN=DIM_K=DIM_V=1024, NH=16, hd=64
#define SEQ   2048
#define DIN   1024
#define MTOT  4096   // B*N
// Q prescale: (1/sqrt(64)) * log2(e) so softmax runs in exp2 domain
#define QSCALE 0.18033688011112042f
#define THR2   11.5f   // defer-max threshold (8 in ln domain)

// ---------------- convert x to bf16 ----------------
__global__ void k_cvt_x(const float* __restrict__ x, u16* __restrict__ xb){
    int i = (blockIdx.x * 256 + threadIdx.x) * 4;
    f32x4 v = *(const f32x4*)(x + i);
    u16x4 o;
    for (int j = 0; j < 4; j++) o[j] = f2bf(v[j]);
    *(u16x4*)(xb + i) = o;
}

// ---------------- transpose W [K][N] -> Wt [N][K] bf16 ----------------
__global__ void k_tw(const float* __restrict__ W, u16* __restrict__ Wt){
    __shared__ float t[32][33];
    int tx = threadIdx.x, ty = threadIdx.y;           // (32,8)
    int n0 = blockIdx.x * 32, k0 = blockIdx.y * 32;
    for (int i = 0; i < 4; i++)
        t[ty + i*8][tx] = W[(size_t)(k0 + ty + i*8) * DIN + n0 + tx];
    __syncthreads();
    for (int i = 0; i < 4; i++)
        Wt[(size_t)(n0 + ty + i*8) * DIN + k0 + tx] = f2bf(t[tx][ty + i*8]);
}

// ---------------- fused QKV projection GEMM ----------------
// C[m][c] = sum_k A[m][k] * Wt[mat][c][k] + bias[mat][c]
// mat 0: Q -> (val+b)*QSCALE, layout [bh][n][64]
// mat 1: K -> val+b,          layout [bh][n][64]
// mat 2: V -> val+b,          layout [bh][dv][n]  (transposed)
__global__ __launch_bounds__(256) void k_projf(const u16* __restrict__ A,
                                               const u16* __restrict__ Wt3,
                                               const float* __restrict__ bq,
                                               const float* __restrict__ bk,
                                               const float* __restrict__ bv,
                                               u16* __restrict__ qb,
                                               u16* __restrict__ kb,
                                               u16* __restrict__ vtb){
    __shared__ u16 As[128 * 32];
    __shared__ u16 Bs[128 * 32];
    int tid = threadIdx.x;
    int l = tid & 63, w = tid >> 6;
    int lq = l & 15, lg = l >> 4;
    int wm = w >> 1, wn = w & 1;
    int by  = blockIdx.y;                 // 0..23
    int mat = by >> 3;                    // 0=Q 1=K 2=V
    int m0 = blockIdx.x * 128, n0 = (by & 7) * 128;
    const u16* Bt = Wt3 + (size_t)mat * DIN * DIN;
    const float* bias = (mat == 0) ? bq : (mat == 1) ? bk : bv;

    f32x4 acc[4][4] = {};

    for (int k0 = 0; k0 < DIN; k0 += 32){
        for (int i = 0; i < 2; i++){
            int eo  = i * 2048 + tid * 8;
            int row = eo >> 5, col = eo & 31;
            async16(&As[eo], A  + (size_t)(m0 + row) * DIN + k0 + col);
            async16(&Bs[eo], Bt + (size_t)(n0 + row) * DIN + k0 + col);
        }
        __syncthreads();
        short8 af[4], bf[4];
        for (int f = 0; f < 4; f++){
            af[f] = *(const short8*)&As[(wm*64 + f*16 + lq) * 32 + lg * 8];
            bf[f] = *(const short8*)&Bs[(wn*64 + f*16 + lq) * 32 + lg * 8];
        }
        for (int fm = 0; fm < 4; fm++)
            for (int fn = 0; fn < 4; fn++)
                acc[fm][fn] = __builtin_amdgcn_mfma_f32_16x16x32_bf16(af[fm], bf[fn], acc[fm][fn], 0, 0, 0);
        __syncthreads();
    }

    for (int fn = 0; fn < 4; fn++){
        int cc = n0 + wn*64 + fn*16 + lq;           // global output column 0..1023
        float bvv = bias[cc];
        int h = cc >> 6, d = cc & 63;
        for (int fm = 0; fm < 4; fm++){
            int mbase = m0 + wm*64 + fm*16 + lg*4;  // global row (b*2048+n)
            int b = mbase >> 11, n = mbase & 2047;
            if (mat == 2){
                u16x4 pv;
                for (int r = 0; r < 4; r++) pv[r] = f2bf(acc[fm][fn][r] + bvv);
                *(u16x4*)&vtb[((size_t)(b*16 + h) * 64 + d) * SEQ + n] = pv;
            } else {
                u16* dst = (mat == 0) ? qb : kb;
                float sc = (mat == 0) ? QSCALE : 1.0f;
                for (int r = 0; r < 4; r++){
                    float v = (acc[fm][fn][r] + bvv) * sc;
                    dst[((size_t)(b*16 + h) * SEQ + (n + r)) * 64 + d] = f2bf(v);
                }
            }
        }
    }
}

// ---------------- flash attention (32x32 MFMA, in-register softmax, KV-split) ----------------
// Q,K: [bh][n][64] bf16 (Q pre-scaled by QSCALE), Vt: [bh][dv][n] bf16
// SPLIT==1: out = normalized fp32 [b][n][1024]
// SPLIT>1 : po[sp] = unnormalized O, mls[sp][bh][n] = {m, ls}
#define MFMA32(a, b, c) __builtin_amdgcn_mfma_f32_32x32x16_bf16(a, b, c, 0, 0, 0)

#define MAKE_PA(dst, S, base) {                                   \
    unsigned a0 = cvtpk(S[base+0], S[base+1]);                    \
    unsigned a1 = cvtpk(S[base+2], S[base+3]);                    \
    unsigned b0 = cvtpk(S[base+4], S[base+5]);                    \
    unsigned b1 = cvtpk(S[base+6], S[base+7]);                    \
    i32x2 r0 = plswap((int)a0, (int)b0);                          \
    i32x2 r1 = plswap((int)a1, (int)b1);                          \
    u32x4 wv = {(unsigned)r0[0], (unsigned)r1[0],                 \
                (unsigned)r0[1], (unsigned)r1[1]};                \
    dst = __builtin_bit_cast(short8, wv); }

template<int SPLIT>
__global__ __launch_bounds__(256) void k_attn(const u16* __restrict__ Q,
                                              const u16* __restrict__ K,
                                              const u16* __restrict__ Vt,
                                              float* __restrict__ out,
                                              float* __restrict__ po,
                                              float* __restrict__ mls){
    int tid = threadIdx.x, l = tid & 63, w = tid >> 6;
    int lq = l & 31, hi = l >> 5;
    int bh = blockIdx.y;                            // 0..31
    int b = bh >> 4, h = bh & 15;
    int q0 = blockIdx.x * 128 + w * 32;
    int sp = blockIdx.z;
    int kvb = sp * (SEQ / SPLIT);

    const u16* Qb = Q  + (size_t)bh * SEQ * 64;
    const u16* Kb = K  + (size_t)bh * SEQ * 64;
    const u16* Vb = Vt + (size_t)bh * 64 * SEQ;

    short8 qf[4];
    #pragma unroll
    for (int ks = 0; ks < 4; ks++)
        qf[ks] = *(const short8*)(Qb + (size_t)(q0 + lq) * 64 + ks*16 + hi*8);

    float m = -INFINITY, ls = 0.f;
    f32x16 o0 = {}, o1 = {};

    for (int kv0 = kvb; kv0 < kvb + SEQ/SPLIT; kv0 += 64){
        // ---- QK^T: St[kc][q] ----
        f32x16 st0 = {}, st1 = {};
        #pragma unroll
        for (int ks = 0; ks < 4; ks++){
            short8 ka = *(const short8*)(Kb + (size_t)(kv0 + lq)      * 64 + ks*16 + hi*8);
            short8 kb = *(const short8*)(Kb + (size_t)(kv0 + 32 + lq) * 64 + ks*16 + hi*8);
            st0 = MFMA32(ka, qf[ks], st0);
            st1 = MFMA32(kb, qf[ks], st1);
        }

        // ---- row max ----
        float p0 = fmaxf(st0[0], st1[0]), p1 = fmaxf(st0[1], st1[1]);
        float p2 = fmaxf(st0[2], st1[2]), p3 = fmaxf(st0[3], st1[3]);
        #pragma unroll
        for (int r = 4; r < 16; r += 4){
            p0 = fmaxf(p0, fmaxf(st0[r+0], st1[r+0]));
            p1 = fmaxf(p1, fmaxf(st0[r+1], st1[r+1]));
            p2 = fmaxf(p2, fmaxf(st0[r+2], st1[r+2]));
            p3 = fmaxf(p3, fmaxf(st0[r+3], st1[r+3]));
        }
        float pm = fmaxf(fmaxf(p0, p1), fmaxf(p2, p3));
        pm = fmaxf(pm, __shfl_xor(pm, 32));

        // ---- defer-max rescale (rare) ----
        if (__any(pm > m + THR2)){
            float mn  = fmaxf(m, pm);
            float fac = ex2(m - mn);                // m=-inf -> 0
            m = mn;
            ls *= fac;
            #pragma unroll
            for (int r = 0; r < 16; r++){
                int row = (r & 3) + 8*(r >> 2) + 4*hi;
                float f = __shfl(fac, row);
                o0[r] *= f; o1[r] *= f;
            }
        }

        // ---- P = exp2(S - m), sum ----
        float psum = 0.f;
        #pragma unroll
        for (int r = 0; r < 16; r++){
            st0[r] = ex2(st0[r] - m); psum += st0[r];
            st1[r] = ex2(st1[r] - m); psum += st1[r];
        }
        psum += __shfl_xor(psum, 32);
        ls += psum;

        // ---- P -> bf16 A-fragments ----
        short8 pa0, pa1, pa2, pa3;
        MAKE_PA(pa0, st0, 0)
        MAKE_PA(pa1, st0, 8)
        MAKE_PA(pa2, st1, 0)
        MAKE_PA(pa3, st1, 8)

        // ---- PV ----
        #pragma unroll
        for (int kct = 0; kct < 4; kct++){
            short8 pf = (kct == 0) ? pa0 : (kct == 1) ? pa1 : (kct == 2) ? pa2 : pa3;
            short8 v0 = *(const short8*)(Vb + (size_t)lq        * SEQ + kv0 + kct*16 + hi*8);
            short8 v1 = *(const short8*)(Vb + (size_t)(32 + lq) * SEQ + kv0 + kct*16 + hi*8);
            o0 = MFMA32(pf, v0, o0);
            o1 = MFMA32(pf, v1, o1);
        }
    }

    if (SPLIT == 1){
        #pragma unroll
        for (int r = 0; r < 16; r++){
            int row = (r & 3) + 8*(r >> 2) + 4*hi;
            float inv = 1.0f / __shfl(ls, row);
            float* op = out + ((size_t)b * SEQ + (q0 + row)) * 1024 + h*64 + lq;
            op[0]  = o0[r] * inv;
            op[32] = o1[r] * inv;
        }
    } else {
        float* pb = po + (size_t)sp * MTOT * 1024;
        #pragma unroll
        for (int r = 0; r < 16; r++){
            int row = (r & 3) + 8*(r >> 2) + 4*hi;
            float* op = pb + ((size_t)b * SEQ + (q0 + row)) * 1024 + h*64 + lq;
            op[0]  = o0[r];
            op[32] = o1[r];
        }
        if (hi == 0){
            float* mp = mls + (((size_t)sp*32 + bh) * SEQ + (q0 + lq)) * 2;
            mp[0] = m; mp[1] = ls;
        }
    }
}

// ---------------- split combine ----------------
template<int S>
__global__ __launch_bounds__(256) void k_comb(const float* __restrict__ po,
                                              const float* __restrict__ mls,
                                              float* __restrict__ out){
    size_t i = ((size_t)blockIdx.x * 256 + threadIdx.x) * 4;
    size_t row = i >> 10;                 // b*2048 + n
    int col = (int)(i & 1023);
    int b = (int)(row >> 11), n = (int)(row & 2047);
    int bh = b*16 + (col >> 6);

    float mv[S], lv[S], wv[S];
    float M = -INFINITY;
    #pragma unroll
    for (int s = 0; s < S; s++){
        const float* p = mls + (((size_t)s*32 + bh) * SEQ + n) * 2;
        mv[s] = p[0]; lv[s] = p[1];
        M = fmaxf(M, mv[s]);
    }
    float L = 0.f;
    #pragma unroll
    for (int s = 0; s < S; s++){ wv[s] = ex2(mv[s] - M); L += wv[s] * lv[s]; }
    float inv = 1.0f / L;
    f32x4 acc = {};
    #pragma unroll
    for (int s = 0; s < S; s++){
        f32x4 v = *(const f32x4*)(po + (size_t)s * MTOT * 1024 + i);
        acc += v * wv[s];
    }
    acc *= inv;
    *(f32x4*)(out + i) = acc;
}

// ---------------- launcher ----------------
extern "C" void kernel_launch(void* const* d_in, const int* in_sizes, int n_in,
                              void* d_out, int out_size, void* d_ws, size_t ws_size,
                              hipStream_t stream){
    const float* x  = (const float*)d_in[0];
    const float* Wq = (const float*)d_in[1];
    const float* bq = (const float*)d_in[2];
    const float* Wk = (const float*)d_in[3];
    const float* bk = (const float*)d_in[4];
    const float* Wv = (const float*)d_in[5];
    const float* bv = (const float*)d_in[6];
    float* out = (float*)d_out;

    const size_t MB = (size_t)1 << 20;
    if (ws_size < 38 * MB) return;

    char* ws = (char*)d_ws;
    u16* xb   = (u16*)(ws);             //  8 MB: x bf16 [4096][1024]
    u16* wt3  = (u16*)(ws +  8 * MB);   //  6 MB: Wt bf16 [3][1024][1024]
    u16* qb   = (u16*)(ws + 14 * MB);   //  8 MB: Q  [32][2048][64]
    u16* kb   = (u16*)(ws + 22 * MB);   //  8 MB: K  [32][2048][64]
    u16* vtb  = (u16*)(ws + 30 * MB);   //  8 MB: Vt [32][64][2048]
    // split scratch: po = SPLIT x 16 MB, mls = SPLIT x 1 MB
    int S = 1;
    if      (ws_size >= 38 * MB + 4 * 17 * MB) S = 4;
    else if (ws_size >= 38 * MB + 2 * 17 * MB) S = 2;
    float* po  = (float*)(ws + 38 * MB);
    float* mls = (float*)(ws + 38 * MB + (size_t)S * 16 * MB);

    k_cvt_x<<<4096, 256, 0, stream>>>(x, xb);
    dim3 tb(32, 8);
    k_tw<<<dim3(32, 32), tb, 0, stream>>>(Wq, wt3);
    k_tw<<<dim3(32, 32), tb, 0, stream>>>(Wk, wt3 + (size_t)DIN*DIN);
    k_tw<<<dim3(32, 32), tb, 0, stream>>>(Wv, wt3 + (size_t)2*DIN*DIN);

    k_projf<<<dim3(32, 24), 256, 0, stream>>>(xb, wt3, bq, bk, bv, qb, kb, vtb);

    if (S == 4){
        k_attn<4><<<dim3(16, 32, 4), 256, 0, stream>>>(qb, kb, vtb, out, po, mls);
        k_comb<4><<<4096, 256, 0, stream>>>(po, mls, out);
    } else if (S == 2){
        k_attn<2><<<dim3(16, 32, 2), 256, 0, stream>>>(qb, kb, vtb, out, po, mls);
        k_comb<2><<<4096, 256, 0, stream>>>(po, mls, out);
    } else {
        k_attn<1><<<dim3(16, 32, 1), 256, 0, stream>>>(qb, kb, vtb, out, po, mls);
    }
}

// Round 4
// 127.508 us; speedup vs baseline: 2.4374x; 1.6119x over previous
//
#include <hip/hip_runtime.h>

#define DI __device__ __forceinline__

typedef unsigned short u16;
typedef short short8 __attribute__((ext_vector_type(8)));
typedef float f32x4 __attribute__((ext_vector_type(4)));
typedef float f32x16 __attribute__((ext_vector_type(16)));
typedef u16 u16x4 __attribute__((ext_vector_type(4)));
typedef unsigned u32x4 __attribute__((ext_vector_type(4)));
typedef int i32x2 __attribute__((ext_vector_type(2)));

// round-to-nearest-even f32 -> bf16
DI u16 f2bf(float f){
    unsigned u = __builtin_bit_cast(unsigned, f);
    u += 0x7FFFu + ((u >> 16) & 1u);
    return (u16)(u >> 16);
}

#if defined(__has_builtin)
#if __has_builtin(__builtin_amdgcn_global_load_lds)
#define HAS_GLL 1
#endif
#if __has_builtin(__builtin_amdgcn_exp2f)
#define HAS_EXP2 1
#endif
#if __has_builtin(__builtin_amdgcn_permlane32_swap)
#define HAS_PL32 1
#endif
#endif

DI void async16(u16* lds, const u16* g){
#ifdef HAS_GLL
    __builtin_amdgcn_global_load_lds(
        (const __attribute__((address_space(1))) unsigned int*)g,
        (__attribute__((address_space(3))) unsigned int*)lds, 16, 0, 0);
#else
    *(short8*)lds = *(const short8*)g;
#endif
}

DI float ex2(float x){
#ifdef HAS_EXP2
    return __builtin_amdgcn_exp2f(x);
#else
    return exp2f(x);
#endif
}

// v_cvt_pk_bf16_f32: word = (bf16(lo) | bf16(hi)<<16)
DI unsigned cvtpk(float lo, float hi){
    unsigned r;
    asm("v_cvt_pk_bf16_f32 %0, %1, %2" : "=v"(r) : "v"(lo), "v"(hi));
    return r;
}

// permlane32_swap: ret[0] = {a[0:31], b[0:31]}, ret[1] = {a[32:63], b[32:63]}
DI i32x2 plswap(int a, int b){
#ifdef HAS_PL32
    return __builtin_amdgcn_permlane32_swap(a, b, false, false);
#else
    i32x2 r;
    int ax = __shfl_xor(a, 32), bx = __shfl_xor(b, 32);
    int hi = (threadIdx.x & 63) >> 5;
    r[0] = hi ? bx : a;
    r[1] = hi ? b : ax;
    return r;
#endif
}

// ---------------- constants ----------------
// B=2, N=2048, DIM_IN=DIM_K=DIM_V=1024, NH=16, hd=64
#define SEQ   2048
#define DIN   1024
#define MTOT  4096   // B*N
// Q prescale: (1/sqrt(64)) * log2(e) so softmax runs in exp2 domain
#define QSCALE 0.18033688011112042f
#define THR2   11.5f   // defer-max threshold (8 in ln domain)

// ---------------- convert x to bf16 ----------------
__global__ void k_cvt_x(const float* __restrict__ x, u16* __restrict__ xb){
    int i = (blockIdx.x * 256 + threadIdx.x) * 4;
    f32x4 v = *(const f32x4*)(x + i);
    u16x4 o;
    for (int j = 0; j < 4; j++) o[j] = f2bf(v[j]);
    *(u16x4*)(xb + i) = o;
}

// ---------------- transpose W [K][N] -> Wt [N][K] bf16 ----------------
__global__ void k_tw(const float* __restrict__ W, u16* __restrict__ Wt){
    __shared__ float t[32][33];
    int tx = threadIdx.x, ty = threadIdx.y;           // (32,8)
    int n0 = blockIdx.x * 32, k0 = blockIdx.y * 32;
    for (int i = 0; i < 4; i++)
        t[ty + i*8][tx] = W[(size_t)(k0 + ty + i*8) * DIN + n0 + tx];
    __syncthreads();
    for (int i = 0; i < 4; i++)
        Wt[(size_t)(n0 + ty + i*8) * DIN + k0 + tx] = f2bf(t[tx][ty + i*8]);
}

// ---------------- fused QKV projection GEMM ----------------
__global__ __launch_bounds__(256) void k_projf(const u16* __restrict__ A,
                                               const u16* __restrict__ Wt3,
                                               const float* __restrict__ bq,
                                               const float* __restrict__ bk,
                                               const float* __restrict__ bv,
                                               u16* __restrict__ qb,
                                               u16* __restrict__ kb,
                                               u16* __restrict__ vtb){
    __shared__ u16 As[128 * 32];
    __shared__ u16 Bs[128 * 32];
    int tid = threadIdx.x;
    int l = tid & 63, w = tid >> 6;
    int lq = l & 15, lg = l >> 4;
    int wm = w >> 1, wn = w & 1;
    int by  = blockIdx.y;                 // 0..23
    int mat = by >> 3;                    // 0=Q 1=K 2=V
    int m0 = blockIdx.x * 128, n0 = (by & 7) * 128;
    const u16* Bt = Wt3 + (size_t)mat * DIN * DIN;
    const float* bias = (mat == 0) ? bq : (mat == 1) ? bk : bv;

    f32x4 acc[4][4] = {};

    for (int k0 = 0; k0 < DIN; k0 += 32){
        for (int i = 0; i < 2; i++){
            int eo  = i * 2048 + tid * 8;
            int row = eo >> 5, col = eo & 31;
            async16(&As[eo], A  + (size_t)(m0 + row) * DIN + k0 + col);
            async16(&Bs[eo], Bt + (size_t)(n0 + row) * DIN + k0 + col);
        }
        __syncthreads();
        short8 af[4], bf[4];
        for (int f = 0; f < 4; f++){
            af[f] = *(const short8*)&As[(wm*64 + f*16 + lq) * 32 + lg * 8];
            bf[f] = *(const short8*)&Bs[(wn*64 + f*16 + lq) * 32 + lg * 8];
        }
        for (int fm = 0; fm < 4; fm++)
            for (int fn = 0; fn < 4; fn++)
                acc[fm][fn] = __builtin_amdgcn_mfma_f32_16x16x32_bf16(af[fm], bf[fn], acc[fm][fn], 0, 0, 0);
        __syncthreads();
    }

    for (int fn = 0; fn < 4; fn++){
        int cc = n0 + wn*64 + fn*16 + lq;
        float bvv = bias[cc];
        int h = cc >> 6, d = cc & 63;
        for (int fm = 0; fm < 4; fm++){
            int mbase = m0 + wm*64 + fm*16 + lg*4;
            int b = mbase >> 11, n = mbase & 2047;
            if (mat == 2){
                u16x4 pv;
                for (int r = 0; r < 4; r++) pv[r] = f2bf(acc[fm][fn][r] + bvv);
                *(u16x4*)&vtb[((size_t)(b*16 + h) * 64 + d) * SEQ + n] = pv;
            } else {
                u16* dst = (mat == 0) ? qb : kb;
                float sc = (mat == 0) ? QSCALE : 1.0f;
                for (int r = 0; r < 4; r++){
                    float v = (acc[fm][fn][r] + bvv) * sc;
                    dst[((size_t)(b*16 + h) * SEQ + (n + r)) * 64 + d] = f2bf(v);
                }
            }
        }
    }
}

// ---------------- flash attention ----------------
// 32x32 MFMA, in-register softmax, LDS-staged K/V (triple-buffered, counted vmcnt).
// Q,K: [bh][n][64] bf16 (Q pre-scaled), Vt: [bh][dv][n] bf16.
// K/V tiles staged via global_load_lds with source-side XOR swizzle
// (chunk ^= row&7 within each 128B row); reads apply the same XOR.
#define MFMA32(a, b, c) __builtin_amdgcn_mfma_f32_32x32x16_bf16(a, b, c, 0, 0, 0)

#define MAKE_PA(dst, S, base) {                                   \
    unsigned a0 = cvtpk(S[base+0], S[base+1]);                    \
    unsigned a1 = cvtpk(S[base+2], S[base+3]);                    \
    unsigned b0 = cvtpk(S[base+4], S[base+5]);                    \
    unsigned b1 = cvtpk(S[base+6], S[base+7]);                    \
    i32x2 r0 = plswap((int)a0, (int)b0);                          \
    i32x2 r1 = plswap((int)a1, (int)b1);                          \
    u32x4 wv = {(unsigned)r0[0], (unsigned)r1[0],                 \
                (unsigned)r0[1], (unsigned)r1[1]};                \
    dst = __builtin_bit_cast(short8, wv); }

template<int SPLIT>
__global__ __launch_bounds__(256, 3) void k_attn(const u16* __restrict__ Q,
                                                 const u16* __restrict__ K,
                                                 const u16* __restrict__ Vt,
                                                 float* __restrict__ out,
                                                 float* __restrict__ po,
                                                 float* __restrict__ mls){
    __shared__ __align__(16) u16 Ks[3][64 * 64];
    __shared__ __align__(16) u16 Vs[3][64 * 64];

    int tid = threadIdx.x, l = tid & 63, w = tid >> 6;
    int lq = l & 31, hi = l >> 5;
    int bh = blockIdx.y;
    int b = bh >> 4, h = bh & 15;
    int q0 = blockIdx.x * 128 + w * 32;
    int sp = blockIdx.z;
    int kvb = sp * (SEQ / SPLIT);
    const int NT = (SEQ / SPLIT) / 64;

    const u16* Qb = Q  + (size_t)bh * SEQ * 64;
    const u16* Kb = K  + (size_t)bh * SEQ * 64;
    const u16* Vb = Vt + (size_t)bh * 64 * SEQ;

    // staging source pointers (source-side swizzle: chunk c -> c ^ (row&7))
    int row0 = tid >> 3;                          // 0..31 (j=0); j=1 adds 32
    int c0   = (tid & 7) ^ (row0 & 7);            // same for j=1 (32 = 0 mod 8)
    const u16* kp0 = Kb + (size_t)(kvb + row0)      * 64 + c0 * 8;
    const u16* kp1 = Kb + (size_t)(kvb + row0 + 32) * 64 + c0 * 8;
    const u16* vp0 = Vb + (size_t)row0        * SEQ + kvb + c0 * 8;
    const u16* vp1 = Vb + (size_t)(row0 + 32) * SEQ + kvb + c0 * 8;
    int d0 = tid * 8, d1 = 2048 + tid * 8;        // linear LDS chunk dests

#define STAGE(bi) {                                               \
    async16(&Ks[bi][d0], kp0); async16(&Ks[bi][d1], kp1);         \
    async16(&Vs[bi][d0], vp0); async16(&Vs[bi][d1], vp1);         \
    kp0 += 64*64; kp1 += 64*64; vp0 += 64; vp1 += 64; }

    // Q fragments: B-operand, col=q=lq, k = ks*16 + hi*8 + 0..7
    short8 qf[4];
    #pragma unroll
    for (int ks = 0; ks < 4; ks++)
        qf[ks] = *(const short8*)(Qb + (size_t)(q0 + lq) * 64 + ks*16 + hi*8);

    STAGE(0)                                       // prologue: tile 0

    float m = -INFINITY, ls = 0.f;
    f32x16 o0 = {}, o1 = {};
    int rx = (lq & 7) << 4;                        // read-side XOR (byte units)

    for (int t = 0; t < NT; t++){
        int cur = t % 3;
        if (t + 1 < NT){
            STAGE((t + 1) % 3)
            asm volatile("s_waitcnt vmcnt(4)" ::: "memory");   // tile t done; t+1 in flight
        } else {
            asm volatile("s_waitcnt vmcnt(0)" ::: "memory");
        }
        __builtin_amdgcn_s_barrier();

        const char* kB = (const char*)&Ks[cur][0];
        const char* vB = (const char*)&Vs[cur][0];

        // ---- QK^T: St[kc][q] ----
        f32x16 st0 = {}, st1 = {};
        #pragma unroll
        for (int ks = 0; ks < 4; ks++){
            int cb = ((ks*2 + hi) << 4) ^ rx;
            short8 ka = *(const short8*)(kB + lq*128        + cb);
            short8 kb = *(const short8*)(kB + (32+lq)*128   + cb);
            st0 = MFMA32(ka, qf[ks], st0);
            st1 = MFMA32(kb, qf[ks], st1);
        }

        // ---- row max ----
        float p0 = fmaxf(st0[0], st1[0]), p1 = fmaxf(st0[1], st1[1]);
        float p2 = fmaxf(st0[2], st1[2]), p3 = fmaxf(st0[3], st1[3]);
        #pragma unroll
        for (int r = 4; r < 16; r += 4){
            p0 = fmaxf(p0, fmaxf(st0[r+0], st1[r+0]));
            p1 = fmaxf(p1, fmaxf(st0[r+1], st1[r+1]));
            p2 = fmaxf(p2, fmaxf(st0[r+2], st1[r+2]));
            p3 = fmaxf(p3, fmaxf(st0[r+3], st1[r+3]));
        }
        float pm = fmaxf(fmaxf(p0, p1), fmaxf(p2, p3));
        pm = fmaxf(pm, __shfl_xor(pm, 32));

        // ---- defer-max rescale (rare) ----
        if (__any(pm > m + THR2)){
            float mn  = fmaxf(m, pm);
            float fac = ex2(m - mn);
            m = mn;
            ls *= fac;
            #pragma unroll
            for (int r = 0; r < 16; r++){
                int row = (r & 3) + 8*(r >> 2) + 4*hi;
                float f = __shfl(fac, row);
                o0[r] *= f; o1[r] *= f;
            }
        }

        // ---- P = exp2(S - m), sum ----
        float psum = 0.f;
        #pragma unroll
        for (int r = 0; r < 16; r++){
            st0[r] = ex2(st0[r] - m); psum += st0[r];
            st1[r] = ex2(st1[r] - m); psum += st1[r];
        }
        psum += __shfl_xor(psum, 32);
        ls += psum;

        // ---- P -> bf16 A-fragments ----
        short8 pa0, pa1, pa2, pa3;
        MAKE_PA(pa0, st0, 0)
        MAKE_PA(pa1, st0, 8)
        MAKE_PA(pa2, st1, 0)
        MAKE_PA(pa3, st1, 8)

        // ---- PV ----
        #pragma unroll
        for (int kct = 0; kct < 4; kct++){
            short8 pf = (kct == 0) ? pa0 : (kct == 1) ? pa1 : (kct == 2) ? pa2 : pa3;
            int cb = ((kct*2 + hi) << 4) ^ rx;
            short8 v0 = *(const short8*)(vB + lq*128      + cb);
            short8 v1 = *(const short8*)(vB + (32+lq)*128 + cb);
            o0 = MFMA32(pf, v0, o0);
            o1 = MFMA32(pf, v1, o1);
        }
        __builtin_amdgcn_s_barrier();              // all reads of cur done before its reuse
    }

    if (SPLIT == 1){
        #pragma unroll
        for (int r = 0; r < 16; r++){
            int row = (r & 3) + 8*(r >> 2) + 4*hi;
            float inv = 1.0f / __shfl(ls, row);
            float* op = out + ((size_t)b * SEQ + (q0 + row)) * 1024 + h*64 + lq;
            op[0]  = o0[r] * inv;
            op[32] = o1[r] * inv;
        }
    } else {
        float* pb = po + (size_t)sp * MTOT * 1024;
        #pragma unroll
        for (int r = 0; r < 16; r++){
            int row = (r & 3) + 8*(r >> 2) + 4*hi;
            float* op = pb + ((size_t)b * SEQ + (q0 + row)) * 1024 + h*64 + lq;
            op[0]  = o0[r];
            op[32] = o1[r];
        }
        if (hi == 0){
            float* mp = mls + (((size_t)sp*32 + bh) * SEQ + (q0 + lq)) * 2;
            mp[0] = m; mp[1] = ls;
        }
    }
#undef STAGE
}

// ---------------- split combine ----------------
template<int S>
__global__ __launch_bounds__(256) void k_comb(const float* __restrict__ po,
                                              const float* __restrict__ mls,
                                              float* __restrict__ out){
    size_t i = ((size_t)blockIdx.x * 256 + threadIdx.x) * 4;
    size_t row = i >> 10;
    int col = (int)(i & 1023);
    int b = (int)(row >> 11), n = (int)(row & 2047);
    int bh = b*16 + (col >> 6);

    float mv[S], lv[S], wv[S];
    float M = -INFINITY;
    #pragma unroll
    for (int s = 0; s < S; s++){
        const float* p = mls + (((size_t)s*32 + bh) * SEQ + n) * 2;
        mv[s] = p[0]; lv[s] = p[1];
        M = fmaxf(M, mv[s]);
    }
    float L = 0.f;
    #pragma unroll
    for (int s = 0; s < S; s++){ wv[s] = ex2(mv[s] - M); L += wv[s] * lv[s]; }
    float inv = 1.0f / L;
    f32x4 acc = {};
    #pragma unroll
    for (int s = 0; s < S; s++){
        f32x4 v = *(const f32x4*)(po + (size_t)s * MTOT * 1024 + i);
        acc += v * wv[s];
    }
    acc *= inv;
    *(f32x4*)(out + i) = acc;
}

// ---------------- launcher ----------------
extern "C" void kernel_launch(void* const* d_in, const int* in_sizes, int n_in,
                              void* d_out, int out_size, void* d_ws, size_t ws_size,
                              hipStream_t stream){
    const float* x  = (const float*)d_in[0];
    const float* Wq = (const float*)d_in[1];
    const float* bq = (const float*)d_in[2];
    const float* Wk = (const float*)d_in[3];
    const float* bk = (const float*)d_in[4];
    const float* Wv = (const float*)d_in[5];
    const float* bv = (const float*)d_in[6];
    float* out = (float*)d_out;

    const size_t MB = (size_t)1 << 20;
    if (ws_size < 38 * MB) return;

    char* ws = (char*)d_ws;
    u16* xb   = (u16*)(ws);             //  8 MB: x bf16 [4096][1024]
    u16* wt3  = (u16*)(ws +  8 * MB);   //  6 MB: Wt bf16 [3][1024][1024]
    u16* qb   = (u16*)(ws + 14 * MB);   //  8 MB: Q  [32][2048][64]
    u16* kb   = (u16*)(ws + 22 * MB);   //  8 MB: K  [32][2048][64]
    u16* vtb  = (u16*)(ws + 30 * MB);   //  8 MB: Vt [32][64][2048]
    int S = (ws_size >= 38 * MB + 2 * 17 * MB) ? 2 : 1;
    float* po  = (float*)(ws + 38 * MB);
    float* mls = (float*)(ws + 38 * MB + (size_t)S * 16 * MB);

    k_cvt_x<<<4096, 256, 0, stream>>>(x, xb);
    dim3 tb(32, 8);
    k_tw<<<dim3(32, 32), tb, 0, stream>>>(Wq, wt3);
    k_tw<<<dim3(32, 32), tb, 0, stream>>>(Wk, wt3 + (size_t)DIN*DIN);
    k_tw<<<dim3(32, 32), tb, 0, stream>>>(Wv, wt3 + (size_t)2*DIN*DIN);

    k_projf<<<dim3(32, 24), 256, 0, stream>>>(xb, wt3, bq, bk, bv, qb, kb, vtb);

    if (S == 2){
        k_attn<2><<<dim3(16, 32, 2), 256, 0, stream>>>(qb, kb, vtb, out, po, mls);
        k_comb<2><<<4096, 256, 0, stream>>>(po, mls, out);
    } else {
        k_attn<1><<<dim3(16, 32, 1), 256, 0, stream>>>(qb, kb, vtb, out, po, mls);
    }
}

// Round 5
// 111.807 us; speedup vs baseline: 2.7797x; 1.1404x over previous
//
#include <hip/hip_runtime.h>

#define DI __device__ __forceinline__

typedef unsigned short u16;
typedef short short8 __attribute__((ext_vector_type(8)));
typedef float f32x4 __attribute__((ext_vector_type(4)));
typedef float f32x16 __attribute__((ext_vector_type(16)));
typedef u16 u16x4 __attribute__((ext_vector_type(4)));
typedef unsigned u32x4 __attribute__((ext_vector_type(4)));
typedef int i32x2 __attribute__((ext_vector_type(2)));

// round-to-nearest-even f32 -> bf16
DI u16 f2bf(float f){
    unsigned u = __builtin_bit_cast(unsigned, f);
    u += 0x7FFFu + ((u >> 16) & 1u);
    return (u16)(u >> 16);
}

#if defined(__has_builtin)
#if __has_builtin(__builtin_amdgcn_global_load_lds)
#define HAS_GLL 1
#endif
#if __has_builtin(__builtin_amdgcn_exp2f)
#define HAS_EXP2 1
#endif
#if __has_builtin(__builtin_amdgcn_permlane32_swap)
#define HAS_PL32 1
#endif
#endif

DI void async16(u16* lds, const u16* g){
#ifdef HAS_GLL
    __builtin_amdgcn_global_load_lds(
        (const __attribute__((address_space(1))) unsigned int*)g,
        (__attribute__((address_space(3))) unsigned int*)lds, 16, 0, 0);
#else
    *(short8*)lds = *(const short8*)g;
#endif
}

DI float ex2(float x){
#ifdef HAS_EXP2
    return __builtin_amdgcn_exp2f(x);
#else
    return exp2f(x);
#endif
}

// v_cvt_pk_bf16_f32: word = (bf16(lo) | bf16(hi)<<16)
DI unsigned cvtpk(float lo, float hi){
    unsigned r;
    asm("v_cvt_pk_bf16_f32 %0, %1, %2" : "=v"(r) : "v"(lo), "v"(hi));
    return r;
}

// permlane32_swap: ret[0] = {a[0:31], b[0:31]}, ret[1] = {a[32:63], b[32:63]}
DI i32x2 plswap(int a, int b){
#ifdef HAS_PL32
    return __builtin_amdgcn_permlane32_swap(a, b, false, false);
#else
    i32x2 r;
    int ax = __shfl_xor(a, 32), bx = __shfl_xor(b, 32);
    int hi = (threadIdx.x & 63) >> 5;
    r[0] = hi ? bx : a;
    r[1] = hi ? b : ax;
    return r;
#endif
}

// ---------------- constants ----------------
// B=2, N=2048, DIM_IN=DIM_K=DIM_V=1024, NH=16, hd=64
#define SEQ   2048
#define DIN   1024
#define MTOT  4096   // B*N
// Q prescale: (1/sqrt(64)) * log2(e) so softmax runs in exp2 domain
#define QSCALE 0.18033688011112042f
#define THR2   11.5f   // defer-max threshold (8 in ln domain)

// ---------------- convert x to bf16 ----------------
__global__ void k_cvt_x(const float* __restrict__ x, u16* __restrict__ xb){
    int i = (blockIdx.x * 256 + threadIdx.x) * 4;
    f32x4 v = *(const f32x4*)(x + i);
    u16x4 o;
    for (int j = 0; j < 4; j++) o[j] = f2bf(v[j]);
    *(u16x4*)(xb + i) = o;
}

// ---------------- transpose W [K][N] -> Wt [N][K] bf16 (all three in one launch) ----------------
__global__ void k_tw3(const float* __restrict__ Wq, const float* __restrict__ Wk,
                      const float* __restrict__ Wv, u16* __restrict__ Wt3){
    const float* W = (blockIdx.z == 0) ? Wq : (blockIdx.z == 1) ? Wk : Wv;
    u16* Wt = Wt3 + (size_t)blockIdx.z * DIN * DIN;
    __shared__ float t[32][33];
    int tx = threadIdx.x, ty = threadIdx.y;           // (32,8)
    int n0 = blockIdx.x * 32, k0 = blockIdx.y * 32;
    for (int i = 0; i < 4; i++)
        t[ty + i*8][tx] = W[(size_t)(k0 + ty + i*8) * DIN + n0 + tx];
    __syncthreads();
    for (int i = 0; i < 4; i++)
        Wt[(size_t)(n0 + ty + i*8) * DIN + k0 + tx] = f2bf(t[tx][ty + i*8]);
}

// ---------------- fused QKV projection GEMM ----------------
// 128x128 tile, BK=32, 3-buffer LDS pipeline with counted vmcnt (R3 attn recipe).
// mat 0: Q -> (val+b)*QSCALE, [bh][n][64]; mat 1: K -> val+b, [bh][n][64];
// mat 2: V -> val+b, [bh][dv][n] (transposed)
__global__ __launch_bounds__(256, 3) void k_projf(const u16* __restrict__ A,
                                                  const u16* __restrict__ Wt3,
                                                  const float* __restrict__ bq,
                                                  const float* __restrict__ bk,
                                                  const float* __restrict__ bv,
                                                  u16* __restrict__ qb,
                                                  u16* __restrict__ kb,
                                                  u16* __restrict__ vtb){
    __shared__ __align__(16) u16 As[3][4096];
    __shared__ __align__(16) u16 Bs[3][4096];
    int tid = threadIdx.x;
    int l = tid & 63, w = tid >> 6;
    int lq = l & 15, lg = l >> 4;
    int wm = w >> 1, wn = w & 1;
    int by  = blockIdx.y;                 // 0..23
    int mat = by >> 3;                    // 0=Q 1=K 2=V
    int m0 = blockIdx.x * 128, n0 = (by & 7) * 128;
    const u16* Bt = Wt3 + (size_t)mat * DIN * DIN;
    const float* bias = (mat == 0) ? bq : (mat == 1) ? bk : bv;

    // staging: thread covers 16B chunks {tid, 256+tid} of each 8KB tile.
    // chunk ci -> (row = ci>>2, col16 = ci&3); linear LDS dest (gll constraint).
    int r0 = tid >> 2, c0 = (tid & 3) * 8;
    const u16* ap0 = A  + (size_t)(m0 + r0)      * DIN + c0;
    const u16* ap1 = A  + (size_t)(m0 + 64 + r0) * DIN + c0;
    const u16* bp0 = Bt + (size_t)(n0 + r0)      * DIN + c0;
    const u16* bp1 = Bt + (size_t)(n0 + 64 + r0) * DIN + c0;
    int d0 = tid * 8, d1 = 2048 + tid * 8;

#define PSTAGE(bi) {                                              \
    async16(&As[bi][d0], ap0); async16(&As[bi][d1], ap1);         \
    async16(&Bs[bi][d0], bp0); async16(&Bs[bi][d1], bp1);         \
    ap0 += 32; ap1 += 32; bp0 += 32; bp1 += 32; }

    f32x4 acc[4][4] = {};
    PSTAGE(0)

    for (int t = 0; t < 32; t++){
        int cur = t % 3;
        if (t + 1 < 32){
            PSTAGE((t + 1) % 3)
            asm volatile("s_waitcnt vmcnt(4)" ::: "memory");   // tile t landed; t+1 in flight
        } else {
            asm volatile("s_waitcnt vmcnt(0)" ::: "memory");
        }
        __builtin_amdgcn_s_barrier();

        short8 af[4], bf[4];
        #pragma unroll
        for (int f = 0; f < 4; f++){
            af[f] = *(const short8*)&As[cur][(wm*64 + f*16 + lq) * 32 + lg * 8];
            bf[f] = *(const short8*)&Bs[cur][(wn*64 + f*16 + lq) * 32 + lg * 8];
        }
        #pragma unroll
        for (int fm = 0; fm < 4; fm++)
            #pragma unroll
            for (int fn = 0; fn < 4; fn++)
                acc[fm][fn] = __builtin_amdgcn_mfma_f32_16x16x32_bf16(af[fm], bf[fn], acc[fm][fn], 0, 0, 0);
        __builtin_amdgcn_s_barrier();              // all reads of cur done before its reuse
    }
#undef PSTAGE

    for (int fn = 0; fn < 4; fn++){
        int cc = n0 + wn*64 + fn*16 + lq;
        float bvv = bias[cc];
        int h = cc >> 6, d = cc & 63;
        for (int fm = 0; fm < 4; fm++){
            int mbase = m0 + wm*64 + fm*16 + lg*4;
            int b = mbase >> 11, n = mbase & 2047;
            if (mat == 2){
                u16x4 pv;
                for (int r = 0; r < 4; r++) pv[r] = f2bf(acc[fm][fn][r] + bvv);
                *(u16x4*)&vtb[((size_t)(b*16 + h) * 64 + d) * SEQ + n] = pv;
            } else {
                u16* dst = (mat == 0) ? qb : kb;
                float sc = (mat == 0) ? QSCALE : 1.0f;
                for (int r = 0; r < 4; r++){
                    float v = (acc[fm][fn][r] + bvv) * sc;
                    dst[((size_t)(b*16 + h) * SEQ + (n + r)) * 64 + d] = f2bf(v);
                }
            }
        }
    }
}

// ---------------- flash attention ----------------
// 32x32 MFMA, in-register softmax, LDS-staged K/V (triple-buffered, counted vmcnt).
#define MFMA32(a, b, c) __builtin_amdgcn_mfma_f32_32x32x16_bf16(a, b, c, 0, 0, 0)

#define MAKE_PA(dst, S, base) {                                   \
    unsigned a0 = cvtpk(S[base+0], S[base+1]);                    \
    unsigned a1 = cvtpk(S[base+2], S[base+3]);                    \
    unsigned b0 = cvtpk(S[base+4], S[base+5]);                    \
    unsigned b1 = cvtpk(S[base+6], S[base+7]);                    \
    i32x2 r0 = plswap((int)a0, (int)b0);                          \
    i32x2 r1 = plswap((int)a1, (int)b1);                          \
    u32x4 wv = {(unsigned)r0[0], (unsigned)r1[0],                 \
                (unsigned)r0[1], (unsigned)r1[1]};                \
    dst = __builtin_bit_cast(short8, wv); }

template<int SPLIT>
__global__ __launch_bounds__(256, 3) void k_attn(const u16* __restrict__ Q,
                                                 const u16* __restrict__ K,
                                                 const u16* __restrict__ Vt,
                                                 float* __restrict__ out,
                                                 float* __restrict__ po,
                                                 float* __restrict__ mls){
    __shared__ __align__(16) u16 Ks[3][64 * 64];
    __shared__ __align__(16) u16 Vs[3][64 * 64];

    int tid = threadIdx.x, l = tid & 63, w = tid >> 6;
    int lq = l & 31, hi = l >> 5;
    int bh = blockIdx.y;
    int b = bh >> 4, h = bh & 15;
    int q0 = blockIdx.x * 128 + w * 32;
    int sp = blockIdx.z;
    int kvb = sp * (SEQ / SPLIT);
    const int NT = (SEQ / SPLIT) / 64;

    const u16* Qb = Q  + (size_t)bh * SEQ * 64;
    const u16* Kb = K  + (size_t)bh * SEQ * 64;
    const u16* Vb = Vt + (size_t)bh * 64 * SEQ;

    // staging source pointers (source-side swizzle: chunk c -> c ^ (row&7))
    int row0 = tid >> 3;                          // 0..31 (j=0); j=1 adds 32
    int c0   = (tid & 7) ^ (row0 & 7);
    const u16* kp0 = Kb + (size_t)(kvb + row0)      * 64 + c0 * 8;
    const u16* kp1 = Kb + (size_t)(kvb + row0 + 32) * 64 + c0 * 8;
    const u16* vp0 = Vb + (size_t)row0        * SEQ + kvb + c0 * 8;
    const u16* vp1 = Vb + (size_t)(row0 + 32) * SEQ + kvb + c0 * 8;
    int d0 = tid * 8, d1 = 2048 + tid * 8;

#define STAGE(bi) {                                               \
    async16(&Ks[bi][d0], kp0); async16(&Ks[bi][d1], kp1);         \
    async16(&Vs[bi][d0], vp0); async16(&Vs[bi][d1], vp1);         \
    kp0 += 64*64; kp1 += 64*64; vp0 += 64; vp1 += 64; }

    short8 qf[4];
    #pragma unroll
    for (int ks = 0; ks < 4; ks++)
        qf[ks] = *(const short8*)(Qb + (size_t)(q0 + lq) * 64 + ks*16 + hi*8);

    STAGE(0)

    float m = -INFINITY, ls = 0.f;
    f32x16 o0 = {}, o1 = {};
    int rx = (lq & 7) << 4;                        // read-side XOR (byte units)

    for (int t = 0; t < NT; t++){
        int cur = t % 3;
        if (t + 1 < NT){
            STAGE((t + 1) % 3)
            asm volatile("s_waitcnt vmcnt(4)" ::: "memory");
        } else {
            asm volatile("s_waitcnt vmcnt(0)" ::: "memory");
        }
        __builtin_amdgcn_s_barrier();

        const char* kB = (const char*)&Ks[cur][0];
        const char* vB = (const char*)&Vs[cur][0];

        // ---- QK^T: St[kc][q] ----
        f32x16 st0 = {}, st1 = {};
        #pragma unroll
        for (int ks = 0; ks < 4; ks++){
            int cb = ((ks*2 + hi) << 4) ^ rx;
            short8 ka = *(const short8*)(kB + lq*128        + cb);
            short8 kb = *(const short8*)(kB + (32+lq)*128   + cb);
            st0 = MFMA32(ka, qf[ks], st0);
            st1 = MFMA32(kb, qf[ks], st1);
        }

        // ---- row max ----
        float p0 = fmaxf(st0[0], st1[0]), p1 = fmaxf(st0[1], st1[1]);
        float p2 = fmaxf(st0[2], st1[2]), p3 = fmaxf(st0[3], st1[3]);
        #pragma unroll
        for (int r = 4; r < 16; r += 4){
            p0 = fmaxf(p0, fmaxf(st0[r+0], st1[r+0]));
            p1 = fmaxf(p1, fmaxf(st0[r+1], st1[r+1]));
            p2 = fmaxf(p2, fmaxf(st0[r+2], st1[r+2]));
            p3 = fmaxf(p3, fmaxf(st0[r+3], st1[r+3]));
        }
        float pm = fmaxf(fmaxf(p0, p1), fmaxf(p2, p3));
        pm = fmaxf(pm, __shfl_xor(pm, 32));

        // ---- defer-max rescale (rare) ----
        if (__any(pm > m + THR2)){
            float mn  = fmaxf(m, pm);
            float fac = ex2(m - mn);
            m = mn;
            ls *= fac;
            #pragma unroll
            for (int r = 0; r < 16; r++){
                int row = (r & 3) + 8*(r >> 2) + 4*hi;
                float f = __shfl(fac, row);
                o0[r] *= f; o1[r] *= f;
            }
        }

        // ---- P = exp2(S - m), sum ----
        float psum = 0.f;
        #pragma unroll
        for (int r = 0; r < 16; r++){
            st0[r] = ex2(st0[r] - m); psum += st0[r];
            st1[r] = ex2(st1[r] - m); psum += st1[r];
        }
        psum += __shfl_xor(psum, 32);
        ls += psum;

        // ---- P -> bf16 A-fragments ----
        short8 pa0, pa1, pa2, pa3;
        MAKE_PA(pa0, st0, 0)
        MAKE_PA(pa1, st0, 8)
        MAKE_PA(pa2, st1, 0)
        MAKE_PA(pa3, st1, 8)

        // ---- PV ----
        #pragma unroll
        for (int kct = 0; kct < 4; kct++){
            short8 pf = (kct == 0) ? pa0 : (kct == 1) ? pa1 : (kct == 2) ? pa2 : pa3;
            int cb = ((kct*2 + hi) << 4) ^ rx;
            short8 v0 = *(const short8*)(vB + lq*128      + cb);
            short8 v1 = *(const short8*)(vB + (32+lq)*128 + cb);
            o0 = MFMA32(pf, v0, o0);
            o1 = MFMA32(pf, v1, o1);
        }
        __builtin_amdgcn_s_barrier();
    }

    if (SPLIT == 1){
        #pragma unroll
        for (int r = 0; r < 16; r++){
            int row = (r & 3) + 8*(r >> 2) + 4*hi;
            float inv = 1.0f / __shfl(ls, row);
            float* op = out + ((size_t)b * SEQ + (q0 + row)) * 1024 + h*64 + lq;
            op[0]  = o0[r] * inv;
            op[32] = o1[r] * inv;
        }
    } else {
        float* pb = po + (size_t)sp * MTOT * 1024;
        #pragma unroll
        for (int r = 0; r < 16; r++){
            int row = (r & 3) + 8*(r >> 2) + 4*hi;
            float* op = pb + ((size_t)b * SEQ + (q0 + row)) * 1024 + h*64 + lq;
            op[0]  = o0[r];
            op[32] = o1[r];
        }
        if (hi == 0){
            float* mp = mls + (((size_t)sp*32 + bh) * SEQ + (q0 + lq)) * 2;
            mp[0] = m; mp[1] = ls;
        }
    }
#undef STAGE
}

// ---------------- split combine ----------------
template<int S>
__global__ __launch_bounds__(256) void k_comb(const float* __restrict__ po,
                                              const float* __restrict__ mls,
                                              float* __restrict__ out){
    size_t i = ((size_t)blockIdx.x * 256 + threadIdx.x) * 4;
    size_t row = i >> 10;
    int col = (int)(i & 1023);
    int b = (int)(row >> 11), n = (int)(row & 2047);
    int bh = b*16 + (col >> 6);

    float mv[S], lv[S], wv[S];
    float M = -INFINITY;
    #pragma unroll
    for (int s = 0; s < S; s++){
        const float* p = mls + (((size_t)s*32 + bh) * SEQ + n) * 2;
        mv[s] = p[0]; lv[s] = p[1];
        M = fmaxf(M, mv[s]);
    }
    float L = 0.f;
    #pragma unroll
    for (int s = 0; s < S; s++){ wv[s] = ex2(mv[s] - M); L += wv[s] * lv[s]; }
    float inv = 1.0f / L;
    f32x4 acc = {};
    #pragma unroll
    for (int s = 0; s < S; s++){
        f32x4 v = *(const f32x4*)(po + (size_t)s * MTOT * 1024 + i);
        acc += v * wv[s];
    }
    acc *= inv;
    *(f32x4*)(out + i) = acc;
}

// ---------------- launcher ----------------
extern "C" void kernel_launch(void* const* d_in, const int* in_sizes, int n_in,
                              void* d_out, int out_size, void* d_ws, size_t ws_size,
                              hipStream_t stream){
    const float* x  = (const float*)d_in[0];
    const float* Wq = (const float*)d_in[1];
    const float* bq = (const float*)d_in[2];
    const float* Wk = (const float*)d_in[3];
    const float* bk = (const float*)d_in[4];
    const float* Wv = (const float*)d_in[5];
    const float* bv = (const float*)d_in[6];
    float* out = (float*)d_out;

    const size_t MB = (size_t)1 << 20;
    if (ws_size < 38 * MB) return;

    char* ws = (char*)d_ws;
    u16* xb   = (u16*)(ws);             //  8 MB: x bf16 [4096][1024]
    u16* wt3  = (u16*)(ws +  8 * MB);   //  6 MB: Wt bf16 [3][1024][1024]
    u16* qb   = (u16*)(ws + 14 * MB);   //  8 MB: Q  [32][2048][64]
    u16* kb   = (u16*)(ws + 22 * MB);   //  8 MB: K  [32][2048][64]
    u16* vtb  = (u16*)(ws + 30 * MB);   //  8 MB: Vt [32][64][2048]
    int S = (ws_size >= 38 * MB + 2 * 17 * MB) ? 2 : 1;
    float* po  = (float*)(ws + 38 * MB);
    float* mls = (float*)(ws + 38 * MB + (size_t)S * 16 * MB);

    k_cvt_x<<<4096, 256, 0, stream>>>(x, xb);
    k_tw3<<<dim3(32, 32, 3), dim3(32, 8), 0, stream>>>(Wq, Wk, Wv, wt3);

    k_projf<<<dim3(32, 24), 256, 0, stream>>>(xb, wt3, bq, bk, bv, qb, kb, vtb);

    if (S == 2){
        k_attn<2><<<dim3(16, 32, 2), 256, 0, stream>>>(qb, kb, vtb, out, po, mls);
        k_comb<2><<<4096, 256, 0, stream>>>(po, mls, out);
    } else {
        k_attn<1><<<dim3(16, 32, 1), 256, 0, stream>>>(qb, kb, vtb, out, po, mls);
    }
}

// Round 6
// 109.888 us; speedup vs baseline: 2.8282x; 1.0175x over previous
//
#include <hip/hip_runtime.h>

#define DI __device__ __forceinline__

typedef unsigned short u16;
typedef short short8 __attribute__((ext_vector_type(8)));
typedef float f32x2 __attribute__((ext_vector_type(2)));
typedef float f32x4 __attribute__((ext_vector_type(4)));
typedef float f32x16 __attribute__((ext_vector_type(16)));
typedef u16 u16x4 __attribute__((ext_vector_type(4)));
typedef unsigned u32x4 __attribute__((ext_vector_type(4)));
typedef int i32x2 __attribute__((ext_vector_type(2)));

// round-to-nearest-even f32 -> bf16
DI u16 f2bf(float f){
    unsigned u = __builtin_bit_cast(unsigned, f);
    u += 0x7FFFu + ((u >> 16) & 1u);
    return (u16)(u >> 16);
}

#if defined(__has_builtin)
#if __has_builtin(__builtin_amdgcn_global_load_lds)
#define HAS_GLL 1
#endif
#if __has_builtin(__builtin_amdgcn_exp2f)
#define HAS_EXP2 1
#endif
#if __has_builtin(__builtin_amdgcn_permlane32_swap)
#define HAS_PL32 1
#endif
#endif

DI void async16(u16* lds, const u16* g){
#ifdef HAS_GLL
    __builtin_amdgcn_global_load_lds(
        (const __attribute__((address_space(1))) unsigned int*)g,
        (__attribute__((address_space(3))) unsigned int*)lds, 16, 0, 0);
#else
    *(short8*)lds = *(const short8*)g;
#endif
}

DI float ex2(float x){
#ifdef HAS_EXP2
    return __builtin_amdgcn_exp2f(x);
#else
    return exp2f(x);
#endif
}

// v_cvt_pk_bf16_f32: word = (bf16(lo) | bf16(hi)<<16)
DI unsigned cvtpk(float lo, float hi){
    unsigned r;
    asm("v_cvt_pk_bf16_f32 %0, %1, %2" : "=v"(r) : "v"(lo), "v"(hi));
    return r;
}

// permlane32_swap: ret[0] = {a[0:31], b[0:31]}, ret[1] = {a[32:63], b[32:63]}
DI i32x2 plswap(int a, int b){
#ifdef HAS_PL32
    return __builtin_amdgcn_permlane32_swap(a, b, false, false);
#else
    i32x2 r;
    int ax = __shfl_xor(a, 32), bx = __shfl_xor(b, 32);
    int hi = (threadIdx.x & 63) >> 5;
    r[0] = hi ? bx : a;
    r[1] = hi ? b : ax;
    return r;
#endif
}

// ---------------- constants ----------------
// B=2, N=2048, DIM_IN=DIM_K=DIM_V=1024, NH=16, hd=64
#define SEQ   2048
#define DIN   1024
#define MTOT  4096   // B*N
// Q prescale: (1/sqrt(64)) * log2(e) so softmax runs in exp2 domain
#define QSCALE 0.18033688011112042f
#define THR2   11.5f   // defer-max threshold (8 in ln domain)

// ---------------- convert x to bf16 ----------------
__global__ void k_cvt_x(const float* __restrict__ x, u16* __restrict__ xb){
    int i = (blockIdx.x * 256 + threadIdx.x) * 4;
    f32x4 v = *(const f32x4*)(x + i);
    u16x4 o;
    for (int j = 0; j < 4; j++) o[j] = f2bf(v[j]);
    *(u16x4*)(xb + i) = o;
}

// ---------------- transpose W [K][N] -> Wt [N][K] bf16 (all three in one launch) ----------------
__global__ void k_tw3(const float* __restrict__ Wq, const float* __restrict__ Wk,
                      const float* __restrict__ Wv, u16* __restrict__ Wt3){
    const float* W = (blockIdx.z == 0) ? Wq : (blockIdx.z == 1) ? Wk : Wv;
    u16* Wt = Wt3 + (size_t)blockIdx.z * DIN * DIN;
    __shared__ float t[32][33];
    int tx = threadIdx.x, ty = threadIdx.y;           // (32,8)
    int n0 = blockIdx.x * 32, k0 = blockIdx.y * 32;
    for (int i = 0; i < 4; i++)
        t[ty + i*8][tx] = W[(size_t)(k0 + ty + i*8) * DIN + n0 + tx];
    __syncthreads();
    for (int i = 0; i < 4; i++)
        Wt[(size_t)(n0 + ty + i*8) * DIN + k0 + tx] = f2bf(t[tx][ty + i*8]);
}

// ---------------- fused QKV projection GEMM ----------------
// 128x128 tile, BK=32, 3-buffer LDS pipeline with counted vmcnt.
__global__ __launch_bounds__(256, 3) void k_projf(const u16* __restrict__ A,
                                                  const u16* __restrict__ Wt3,
                                                  const float* __restrict__ bq,
                                                  const float* __restrict__ bk,
                                                  const float* __restrict__ bv,
                                                  u16* __restrict__ qb,
                                                  u16* __restrict__ kb,
                                                  u16* __restrict__ vtb){
    __shared__ __align__(16) u16 As[3][4096];
    __shared__ __align__(16) u16 Bs[3][4096];
    int tid = threadIdx.x;
    int l = tid & 63, w = tid >> 6;
    int lq = l & 15, lg = l >> 4;
    int wm = w >> 1, wn = w & 1;
    int by  = blockIdx.y;                 // 0..23
    int mat = by >> 3;                    // 0=Q 1=K 2=V
    int m0 = blockIdx.x * 128, n0 = (by & 7) * 128;
    const u16* Bt = Wt3 + (size_t)mat * DIN * DIN;
    const float* bias = (mat == 0) ? bq : (mat == 1) ? bk : bv;

    int r0 = tid >> 2, c0 = (tid & 3) * 8;
    const u16* ap0 = A  + (size_t)(m0 + r0)      * DIN + c0;
    const u16* ap1 = A  + (size_t)(m0 + 64 + r0) * DIN + c0;
    const u16* bp0 = Bt + (size_t)(n0 + r0)      * DIN + c0;
    const u16* bp1 = Bt + (size_t)(n0 + 64 + r0) * DIN + c0;
    int d0 = tid * 8, d1 = 2048 + tid * 8;

#define PSTAGE(bi) {                                              \
    async16(&As[bi][d0], ap0); async16(&As[bi][d1], ap1);         \
    async16(&Bs[bi][d0], bp0); async16(&Bs[bi][d1], bp1);         \
    ap0 += 32; ap1 += 32; bp0 += 32; bp1 += 32; }

    f32x4 acc[4][4] = {};
    PSTAGE(0)

    for (int t = 0; t < 32; t++){
        int cur = t % 3;
        if (t + 1 < 32){
            PSTAGE((t + 1) % 3)
            asm volatile("s_waitcnt vmcnt(4)" ::: "memory");
        } else {
            asm volatile("s_waitcnt vmcnt(0)" ::: "memory");
        }
        __builtin_amdgcn_s_barrier();

        short8 af[4], bf[4];
        #pragma unroll
        for (int f = 0; f < 4; f++){
            af[f] = *(const short8*)&As[cur][(wm*64 + f*16 + lq) * 32 + lg * 8];
            bf[f] = *(const short8*)&Bs[cur][(wn*64 + f*16 + lq) * 32 + lg * 8];
        }
        __builtin_amdgcn_s_setprio(1);
        #pragma unroll
        for (int fm = 0; fm < 4; fm++)
            #pragma unroll
            for (int fn = 0; fn < 4; fn++)
                acc[fm][fn] = __builtin_amdgcn_mfma_f32_16x16x32_bf16(af[fm], bf[fn], acc[fm][fn], 0, 0, 0);
        __builtin_amdgcn_s_setprio(0);
        __builtin_amdgcn_s_barrier();
    }
#undef PSTAGE

    for (int fn = 0; fn < 4; fn++){
        int cc = n0 + wn*64 + fn*16 + lq;
        float bvv = bias[cc];
        int h = cc >> 6, d = cc & 63;
        for (int fm = 0; fm < 4; fm++){
            int mbase = m0 + wm*64 + fm*16 + lg*4;
            int b = mbase >> 11, n = mbase & 2047;
            if (mat == 2){
                u16x4 pv;
                for (int r = 0; r < 4; r++) pv[r] = f2bf(acc[fm][fn][r] + bvv);
                *(u16x4*)&vtb[((size_t)(b*16 + h) * 64 + d) * SEQ + n] = pv;
            } else {
                u16* dst = (mat == 0) ? qb : kb;
                float sc = (mat == 0) ? QSCALE : 1.0f;
                for (int r = 0; r < 4; r++){
                    float v = (acc[fm][fn][r] + bvv) * sc;
                    dst[((size_t)(b*16 + h) * SEQ + (n + r)) * 64 + d] = f2bf(v);
                }
            }
        }
    }
}

// ---------------- flash attention ----------------
// 32x32 MFMA, in-register softmax, double-buffered LDS K/V (2-phase schedule):
//   STAGE(next) at top of iter (post-barrier, race-free) -> compute(cur)
//   -> vmcnt(0) (drain covered by compute) -> one s_barrier.
// 32 KB LDS + launch_bounds(256,4) -> 4 blocks/CU; grid 1024 = fully co-resident.
#define MFMA32(a, b, c) __builtin_amdgcn_mfma_f32_32x32x16_bf16(a, b, c, 0, 0, 0)

#define MAKE_PA(dst, S, base) {                                   \
    unsigned a0 = cvtpk(S[base+0], S[base+1]);                    \
    unsigned a1 = cvtpk(S[base+2], S[base+3]);                    \
    unsigned b0 = cvtpk(S[base+4], S[base+5]);                    \
    unsigned b1 = cvtpk(S[base+6], S[base+7]);                    \
    i32x2 r0 = plswap((int)a0, (int)b0);                          \
    i32x2 r1 = plswap((int)a1, (int)b1);                          \
    u32x4 wv = {(unsigned)r0[0], (unsigned)r1[0],                 \
                (unsigned)r0[1], (unsigned)r1[1]};                \
    dst = __builtin_bit_cast(short8, wv); }

template<int SPLIT>
__global__ __launch_bounds__(256, 4) void k_attn(const u16* __restrict__ Q,
                                                 const u16* __restrict__ K,
                                                 const u16* __restrict__ Vt,
                                                 float* __restrict__ out,
                                                 float* __restrict__ po,
                                                 float* __restrict__ mls){
    __shared__ __align__(16) u16 Ks[2][64 * 64];
    __shared__ __align__(16) u16 Vs[2][64 * 64];

    int tid = threadIdx.x, l = tid & 63, w = tid >> 6;
    int lq = l & 31, hi = l >> 5;
    int bh = blockIdx.y;
    int b = bh >> 4, h = bh & 15;
    int q0 = blockIdx.x * 128 + w * 32;
    int sp = blockIdx.z;
    int kvb = sp * (SEQ / SPLIT);
    const int NT = (SEQ / SPLIT) / 64;

    const u16* Qb = Q  + (size_t)bh * SEQ * 64;
    const u16* Kb = K  + (size_t)bh * SEQ * 64;
    const u16* Vb = Vt + (size_t)bh * 64 * SEQ;

    // staging source pointers (source-side swizzle: chunk c -> c ^ (row&7))
    int row0 = tid >> 3;                          // 0..31 (j=0); j=1 adds 32
    int c0   = (tid & 7) ^ (row0 & 7);
    const u16* kp0 = Kb + (size_t)(kvb + row0)      * 64 + c0 * 8;
    const u16* kp1 = Kb + (size_t)(kvb + row0 + 32) * 64 + c0 * 8;
    const u16* vp0 = Vb + (size_t)row0        * SEQ + kvb + c0 * 8;
    const u16* vp1 = Vb + (size_t)(row0 + 32) * SEQ + kvb + c0 * 8;
    int d0 = tid * 8, d1 = 2048 + tid * 8;

#define STAGE(bi) {                                               \
    async16(&Ks[bi][d0], kp0); async16(&Ks[bi][d1], kp1);         \
    async16(&Vs[bi][d0], vp0); async16(&Vs[bi][d1], vp1);         \
    kp0 += 64*64; kp1 += 64*64; vp0 += 64; vp1 += 64; }

    short8 qf[4];
    #pragma unroll
    for (int ks = 0; ks < 4; ks++)
        qf[ks] = *(const short8*)(Qb + (size_t)(q0 + lq) * 64 + ks*16 + hi*8);

    STAGE(0)

    float m = -INFINITY, ls = 0.f;
    f32x16 o0 = {}, o1 = {};
    int rx = (lq & 7) << 4;                        // read-side XOR (byte units)

    for (int t = 0; t < NT; t++){
        int cur = t & 1;
        if (t + 1 < NT) STAGE(cur ^ 1)             // issued post prior barrier -> race-free
        if (t == 0){
            if (NT > 1) asm volatile("s_waitcnt vmcnt(4)" ::: "memory");
            else        asm volatile("s_waitcnt vmcnt(0)" ::: "memory");
            __builtin_amdgcn_s_barrier();
        }

        const char* kB = (const char*)&Ks[cur][0];
        const char* vB = (const char*)&Vs[cur][0];

        // ---- QK^T: St[kc][q] ----
        f32x16 st0 = {}, st1 = {};
        __builtin_amdgcn_s_setprio(1);
        #pragma unroll
        for (int ks = 0; ks < 4; ks++){
            int cb = ((ks*2 + hi) << 4) ^ rx;
            short8 ka = *(const short8*)(kB + lq*128        + cb);
            short8 kb = *(const short8*)(kB + (32+lq)*128   + cb);
            st0 = MFMA32(ka, qf[ks], st0);
            st1 = MFMA32(kb, qf[ks], st1);
        }
        __builtin_amdgcn_s_setprio(0);

        // ---- row max ----
        float p0 = fmaxf(st0[0], st1[0]), p1 = fmaxf(st0[1], st1[1]);
        float p2 = fmaxf(st0[2], st1[2]), p3 = fmaxf(st0[3], st1[3]);
        #pragma unroll
        for (int r = 4; r < 16; r += 4){
            p0 = fmaxf(p0, fmaxf(st0[r+0], st1[r+0]));
            p1 = fmaxf(p1, fmaxf(st0[r+1], st1[r+1]));
            p2 = fmaxf(p2, fmaxf(st0[r+2], st1[r+2]));
            p3 = fmaxf(p3, fmaxf(st0[r+3], st1[r+3]));
        }
        float pm = fmaxf(fmaxf(p0, p1), fmaxf(p2, p3));
        pm = fmaxf(pm, __shfl_xor(pm, 32));

        // ---- defer-max rescale (rare) ----
        if (__any(pm > m + THR2)){
            float mn  = fmaxf(m, pm);
            float fac = ex2(m - mn);
            m = mn;
            ls *= fac;
            #pragma unroll
            for (int r = 0; r < 16; r++){
                int row = (r & 3) + 8*(r >> 2) + 4*hi;
                float f = __shfl(fac, row);
                o0[r] *= f; o1[r] *= f;
            }
        }

        // ---- P = exp2(S - m), packed-pair sum ----
        f32x2 ps = {0.f, 0.f};
        #pragma unroll
        for (int r = 0; r < 16; r += 2){
            st0[r]   = ex2(st0[r]   - m);
            st0[r+1] = ex2(st0[r+1] - m);
            st1[r]   = ex2(st1[r]   - m);
            st1[r+1] = ex2(st1[r+1] - m);
            f32x2 a = {st0[r], st0[r+1]};
            f32x2 c = {st1[r], st1[r+1]};
            ps += a + c;
        }
        float psum = ps[0] + ps[1];
        psum += __shfl_xor(psum, 32);
        ls += psum;

        // ---- P -> bf16 A-fragments ----
        short8 pa0, pa1, pa2, pa3;
        MAKE_PA(pa0, st0, 0)
        MAKE_PA(pa1, st0, 8)
        MAKE_PA(pa2, st1, 0)
        MAKE_PA(pa3, st1, 8)

        // ---- PV ----
        __builtin_amdgcn_s_setprio(1);
        #pragma unroll
        for (int kct = 0; kct < 4; kct++){
            short8 pf = (kct == 0) ? pa0 : (kct == 1) ? pa1 : (kct == 2) ? pa2 : pa3;
            int cb = ((kct*2 + hi) << 4) ^ rx;
            short8 v0 = *(const short8*)(vB + lq*128      + cb);
            short8 v1 = *(const short8*)(vB + (32+lq)*128 + cb);
            o0 = MFMA32(pf, v0, o0);
            o1 = MFMA32(pf, v1, o1);
        }
        __builtin_amdgcn_s_setprio(0);

        asm volatile("s_waitcnt vmcnt(0)" ::: "memory");   // next tile landed (covered by compute)
        __builtin_amdgcn_s_barrier();
    }

    if (SPLIT == 1){
        #pragma unroll
        for (int r = 0; r < 16; r++){
            int row = (r & 3) + 8*(r >> 2) + 4*hi;
            float inv = 1.0f / __shfl(ls, row);
            float* op = out + ((size_t)b * SEQ + (q0 + row)) * 1024 + h*64 + lq;
            op[0]  = o0[r] * inv;
            op[32] = o1[r] * inv;
        }
    } else {
        float* pb = po + (size_t)sp * MTOT * 1024;
        #pragma unroll
        for (int r = 0; r < 16; r++){
            int row = (r & 3) + 8*(r >> 2) + 4*hi;
            float* op = pb + ((size_t)b * SEQ + (q0 + row)) * 1024 + h*64 + lq;
            op[0]  = o0[r];
            op[32] = o1[r];
        }
        if (hi == 0){
            float* mp = mls + (((size_t)sp*32 + bh) * SEQ + (q0 + lq)) * 2;
            mp[0] = m; mp[1] = ls;
        }
    }
#undef STAGE
}

// ---------------- split combine ----------------
template<int S>
__global__ __launch_bounds__(256) void k_comb(const float* __restrict__ po,
                                              const float* __restrict__ mls,
                                              float* __restrict__ out){
    size_t i = ((size_t)blockIdx.x * 256 + threadIdx.x) * 4;
    size_t row = i >> 10;
    int col = (int)(i & 1023);
    int b = (int)(row >> 11), n = (int)(row & 2047);
    int bh = b*16 + (col >> 6);

    float mv[S], lv[S], wv[S];
    float M = -INFINITY;
    #pragma unroll
    for (int s = 0; s < S; s++){
        const float* p = mls + (((size_t)s*32 + bh) * SEQ + n) * 2;
        mv[s] = p[0]; lv[s] = p[1];
        M = fmaxf(M, mv[s]);
    }
    float L = 0.f;
    #pragma unroll
    for (int s = 0; s < S; s++){ wv[s] = ex2(mv[s] - M); L += wv[s] * lv[s]; }
    float inv = 1.0f / L;
    f32x4 acc = {};
    #pragma unroll
    for (int s = 0; s < S; s++){
        f32x4 v = *(const f32x4*)(po + (size_t)s * MTOT * 1024 + i);
        acc += v * wv[s];
    }
    acc *= inv;
    *(f32x4*)(out + i) = acc;
}

// ---------------- launcher ----------------
extern "C" void kernel_launch(void* const* d_in, const int* in_sizes, int n_in,
                              void* d_out, int out_size, void* d_ws, size_t ws_size,
                              hipStream_t stream){
    const float* x  = (const float*)d_in[0];
    const float* Wq = (const float*)d_in[1];
    const float* bq = (const float*)d_in[2];
    const float* Wk = (const float*)d_in[3];
    const float* bk = (const float*)d_in[4];
    const float* Wv = (const float*)d_in[5];
    const float* bv = (const float*)d_in[6];
    float* out = (float*)d_out;

    const size_t MB = (size_t)1 << 20;
    if (ws_size < 38 * MB) return;

    char* ws = (char*)d_ws;
    u16* xb   = (u16*)(ws);             //  8 MB: x bf16 [4096][1024]
    u16* wt3  = (u16*)(ws +  8 * MB);   //  6 MB: Wt bf16 [3][1024][1024]
    u16* qb   = (u16*)(ws + 14 * MB);   //  8 MB: Q  [32][2048][64]
    u16* kb   = (u16*)(ws + 22 * MB);   //  8 MB: K  [32][2048][64]
    u16* vtb  = (u16*)(ws + 30 * MB);   //  8 MB: Vt [32][64][2048]
    int S = (ws_size >= 38 * MB + 2 * 17 * MB) ? 2 : 1;
    float* po  = (float*)(ws + 38 * MB);
    float* mls = (float*)(ws + 38 * MB + (size_t)S * 16 * MB);

    k_cvt_x<<<4096, 256, 0, stream>>>(x, xb);
    k_tw3<<<dim3(32, 32, 3), dim3(32, 8), 0, stream>>>(Wq, Wk, Wv, wt3);

    k_projf<<<dim3(32, 24), 256, 0, stream>>>(xb, wt3, bq, bk, bv, qb, kb, vtb);

    if (S == 2){
        k_attn<2><<<dim3(16, 32, 2), 256, 0, stream>>>(qb, kb, vtb, out, po, mls);
        k_comb<2><<<4096, 256, 0, stream>>>(po, mls, out);
    } else {
        k_attn<1><<<dim3(16, 32, 1), 256, 0, stream>>>(qb, kb, vtb, out, po, mls);
    }
}